// Round 6
// baseline (247.294 us; speedup 1.0000x reference)
//
#include <hip/hip_runtime.h>
#include <hip/hip_bf16.h>
#include <math.h>

// B=32,T=512 -> NTOK=16384 tokens; F=64; H=64; E=32
#define NTOK 16384

typedef __attribute__((ext_vector_type(8))) short short8;   // 8 bf16 (MFMA A/B)
typedef __attribute__((ext_vector_type(4))) float f32x4;    // MFMA acc
typedef __attribute__((ext_vector_type(4))) unsigned int uint32x4;

__device__ __forceinline__ unsigned pack_bf16(float a, float b) {
    union { __hip_bfloat162 h; unsigned u; } cv;
    cv.h = __float22bfloat162_rn(make_float2(a, b));
    return cv.u;
}
__device__ __forceinline__ float eluf(float z) {
    return z > 0.0f ? z : (__expf(z) - 1.0f);
}

// A-gen for one f: 16 elu-sites -> two bf16x8 fragments.
// Contribution order to acc[] preserved exactly vs the validated v6 kernel.
__device__ __forceinline__ void agen16(const float* __restrict__ wb,
                                       float xv, float wt,
                                       short8& a0, short8& a1) {
    const float4 wa  = *(const float4*)(wb);
    const float4 wbv = *(const float4*)(wb + 4);
    const float4 ba  = *(const float4*)(wb + 64);
    const float4 bb  = *(const float4*)(wb + 68);
    uint4 v0;
    v0.x = pack_bf16(wt * eluf(fmaf(xv, wa.x, ba.x)),
                     wt * eluf(fmaf(xv, wa.y, ba.y)));
    v0.y = pack_bf16(wt * eluf(fmaf(xv, wa.z, ba.z)),
                     wt * eluf(fmaf(xv, wa.w, ba.w)));
    v0.z = pack_bf16(wt * eluf(fmaf(xv, wbv.x, bb.x)),
                     wt * eluf(fmaf(xv, wbv.y, bb.y)));
    v0.w = pack_bf16(wt * eluf(fmaf(xv, wbv.z, bb.z)),
                     wt * eluf(fmaf(xv, wbv.w, bb.w)));
    a0 = *(short8*)&v0;
    const float4 wc = *(const float4*)(wb + 32);
    const float4 wd = *(const float4*)(wb + 36);
    const float4 bc = *(const float4*)(wb + 96);
    const float4 bd = *(const float4*)(wb + 100);
    uint4 v1;
    v1.x = pack_bf16(wt * eluf(fmaf(xv, wc.x, bc.x)),
                     wt * eluf(fmaf(xv, wc.y, bc.y)));
    v1.y = pack_bf16(wt * eluf(fmaf(xv, wc.z, bc.z)),
                     wt * eluf(fmaf(xv, wc.w, bc.w)));
    v1.z = pack_bf16(wt * eluf(fmaf(xv, wd.x, bd.x)),
                     wt * eluf(fmaf(xv, wd.y, bd.y)));
    v1.w = pack_bf16(wt * eluf(fmaf(xv, wd.z, bd.z)),
                     wt * eluf(fmaf(xv, wd.w, bd.w)));
    a1 = *(short8*)&v1;
}

// ---------------- prepass: fragment-major bf16 B images ----------------
__global__ __launch_bounds__(256)
void prepass(const float* __restrict__ ew3, const float* __restrict__ eb3,
             unsigned short* __restrict__ ws) {
    __shared__ float tile[64 * 65];
    const int bid = blockIdx.x, tid = threadIdx.x;
    const float* src = (bid < 64) ? (ew3 + (size_t)bid * 4096) : eb3;

    const int r = tid >> 2, c0 = (tid & 3) * 16;
    #pragma unroll
    for (int j = 0; j < 4; ++j) {
        float4 v = *(const float4*)(src + r * 64 + c0 + j * 4);
        tile[r * 65 + c0 + j * 4 + 0] = v.x;
        tile[r * 65 + c0 + j * 4 + 1] = v.y;
        tile[r * 65 + c0 + j * 4 + 2] = v.z;
        tile[r * 65 + c0 + j * 4 + 3] = v.w;
    }
    __syncthreads();

    uint4* dst = (uint4*)(ws + (size_t)bid * 4096);
    #pragma unroll
    for (int it = 0; it < 2; ++it) {
        const int idx = tid + it * 256;
        const int c = idx >> 8, u = (idx >> 6) & 3, l = idx & 63;
        const int mm = l & 15, q = (l >> 4) & 3;
        const int rb = c * 32 + q * 8, col = u * 16 + mm;
        unsigned pw[4];
        #pragma unroll
        for (int p = 0; p < 4; ++p)
            pw[p] = pack_bf16(tile[(rb + 2 * p) * 65 + col],
                              tile[(rb + 2 * p + 1) * 65 + col]);
        uint4 pk; pk.x = pw[0]; pk.y = pw[1]; pk.z = pw[2]; pk.w = pw[3];
        dst[idx] = pk;
    }
}

// ---------------- fused prepass + gating kernel ----------------
__global__ __launch_bounds__(256)
void prep_gate(const float* __restrict__ ew3, const float* __restrict__ eb3,
               const float* __restrict__ x,   const float* __restrict__ s,
               const float* __restrict__ fw1, const float* __restrict__ fb1,
               const float* __restrict__ fw2, const float* __restrict__ fb2,
               const float* __restrict__ fw3, const float* __restrict__ fb3,
               unsigned short* __restrict__ img, float* __restrict__ wtg)
{
    __shared__ float smem[64 * 65];
    const int tid = threadIdx.x;

    if (blockIdx.x < 65) {
        const int bid = blockIdx.x;
        const float* src = (bid < 64) ? (ew3 + (size_t)bid * 4096) : eb3;
        const int r = tid >> 2, c0 = (tid & 3) * 16;
        #pragma unroll
        for (int j = 0; j < 4; ++j) {
            float4 v = *(const float4*)(src + r * 64 + c0 + j * 4);
            smem[r * 65 + c0 + j * 4 + 0] = v.x;
            smem[r * 65 + c0 + j * 4 + 1] = v.y;
            smem[r * 65 + c0 + j * 4 + 2] = v.z;
            smem[r * 65 + c0 + j * 4 + 3] = v.w;
        }
        __syncthreads();
        uint4* dst = (uint4*)(img + (size_t)bid * 4096);
        #pragma unroll
        for (int it = 0; it < 2; ++it) {
            const int idx = tid + it * 256;
            const int c = idx >> 8, u = (idx >> 6) & 3, l = idx & 63;
            const int mm = l & 15, q = (l >> 4) & 3;
            const int rb = c * 32 + q * 8, col = u * 16 + mm;
            unsigned pw[4];
            #pragma unroll
            for (int p = 0; p < 4; ++p)
                pw[p] = pack_bf16(smem[(rb + 2 * p) * 65 + col],
                                  smem[(rb + 2 * p + 1) * 65 + col]);
            uint4 pk; pk.x = pw[0]; pk.y = pw[1]; pk.z = pw[2]; pk.w = pw[3];
            dst[idx] = pk;
        }
        return;
    }

    float* xls = smem;                 // [16][68]
    float* egs = smem + 16 * 68;       // [16][64]
    const int gb = blockIdx.x - 65;
    const int tokbase = gb * 16;
    const int wv = tid >> 6, lane = tid & 63;

    {
        const int t = tid >> 4, fq = (tid & 15) * 4;
        *(float4*)&xls[t * 68 + fq] =
            *(const float4*)(x + (size_t)(tokbase + t) * 64 + fq);
    }
    __syncthreads();

    const int t0w = wv * 4;
    const float* sw = s + (size_t)(tokbase + t0w) * 32;
    float g[4];
    const float b0 = fb1[lane] + fb2[lane];
    #pragma unroll
    for (int t = 0; t < 4; ++t) g[t] = b0;
    #pragma unroll 2
    for (int f = 0; f < 64; f += 4) {
        const float w0 = fw1[(f + 0) * 64 + lane];
        const float w1 = fw1[(f + 1) * 64 + lane];
        const float w2 = fw1[(f + 2) * 64 + lane];
        const float w3v = fw1[(f + 3) * 64 + lane];
        #pragma unroll
        for (int t = 0; t < 4; ++t) {
            const float4 xa = *(const float4*)&xls[(t0w + t) * 68 + f];
            g[t] = fmaf(xa.x, w0, fmaf(xa.y, w1, fmaf(xa.z, w2, fmaf(xa.w, w3v, g[t]))));
        }
    }
    #pragma unroll 2
    for (int e = 0; e < 32; e += 4) {
        const float w0 = fw2[(e + 0) * 64 + lane];
        const float w1 = fw2[(e + 1) * 64 + lane];
        const float w2 = fw2[(e + 2) * 64 + lane];
        const float w3v = fw2[(e + 3) * 64 + lane];
        #pragma unroll
        for (int t = 0; t < 4; ++t) {
            const float4 sa = *(const float4*)(sw + t * 32 + e);
            g[t] = fmaf(sa.x, w0, fmaf(sa.y, w1, fmaf(sa.z, w2, fmaf(sa.w, w3v, g[t]))));
        }
    }
    #pragma unroll
    for (int t = 0; t < 4; ++t) egs[(t0w + t) * 64 + lane] = eluf(g[t]);

    float lg[4];
    const float b3 = fb3[lane];
    #pragma unroll
    for (int t = 0; t < 4; ++t) lg[t] = b3;
    #pragma unroll 2
    for (int h = 0; h < 64; h += 4) {
        const float w0 = fw3[(h + 0) * 64 + lane];
        const float w1 = fw3[(h + 1) * 64 + lane];
        const float w2 = fw3[(h + 2) * 64 + lane];
        const float w3v = fw3[(h + 3) * 64 + lane];
        #pragma unroll
        for (int t = 0; t < 4; ++t) {
            const float4 ev = *(const float4*)&egs[(t0w + t) * 64 + h];
            lg[t] = fmaf(ev.x, w0, fmaf(ev.y, w1, fmaf(ev.z, w2, fmaf(ev.w, w3v, lg[t]))));
        }
    }
    #pragma unroll
    for (int t = 0; t < 4; ++t) {
        float mx = lg[t];
        #pragma unroll
        for (int off = 32; off > 0; off >>= 1) mx = fmaxf(mx, __shfl_xor(mx, off));
        const float p = __expf(lg[t] - mx);
        float sm = p;
        #pragma unroll
        for (int off = 32; off > 0; off >>= 1) sm += __shfl_xor(sm, off);
        wtg[(size_t)(tokbase + t0w + t) * 64 + lane] = p / sm;
    }
}

// ---------------- main kernel v7: v6 + DEAD diagnostic half-pass ----------------
// The dead pass (8 f-values, acc2, asm keep-alive) runs BEFORE the real loop so
// peak register pressure stays ~105 (acc not yet live). Purpose: push this
// dispatch's duration above the harness's ~41us workspace fills so its rocprof
// counters surface in top-5. Real-output math identical to the validated v6.
__global__ __launch_bounds__(512, 4)
void moe_main7(const float* __restrict__ x,
               const float* __restrict__ ew1, const float* __restrict__ eb1,
               const unsigned short* __restrict__ img,
               const float* __restrict__ wtg,
               float* __restrict__ out)
{
    __shared__ __align__(16) float xls[32 * 68];
    __shared__ __align__(16) float wls[32 * 68];
    __shared__ __align__(16) float wbped[64 * 128];

    const int tid = threadIdx.x;
    const int wv = tid >> 6, lane = tid & 63;
    const int m = tid & 15, quad = (tid >> 4) & 3;
    const int tile = wv & 1, g = wv >> 1;
    const int f0 = g * 16;
    const int trow = tile * 16 + m;
    const int tokbase = blockIdx.x * 32;

    {
        const int t = tid >> 4, fq = (tid & 15) * 4;
        *(float4*)&xls[t * 68 + fq] =
            *(const float4*)(x + (size_t)(tokbase + t) * 64 + fq);
        *(float4*)&wls[t * 68 + fq] =
            *(const float4*)(wtg + (size_t)(tokbase + t) * 64 + fq);
        #pragma unroll
        for (int k = 0; k < 2; ++k) {
            const int idx = tid + k * 512;
            const int fr = idx >> 4, c4 = (idx & 15) * 4;
            *(float4*)&wbped[fr * 128 + c4]      = *(const float4*)(ew1 + fr * 64 + c4);
            *(float4*)&wbped[fr * 128 + 64 + c4] = *(const float4*)(eb1 + fr * 64 + c4);
        }
    }
    __syncthreads();

    // ==== DEAD diagnostic half-pass: same dbuf structure, 8 f-values ====
    {
        f32x4 acc2[4];
        #pragma unroll
        for (int u = 0; u < 4; ++u) acc2[u] = (f32x4){0.f, 0.f, 0.f, 0.f};
        const uint4* b2 = (const uint4*)img + (size_t)f0 * 512 + lane;
        uint4 C0[8], C1[8];
        #pragma unroll
        for (int j = 0; j < 8; ++j) C0[j] = b2[j * 64];
        b2 += 512;
        const float* xq = &xls[trow * 68 + f0];
        const float* wq = &wls[trow * 68 + f0];
        const float* wb2 = &wbped[f0 * 128 + quad * 8];
        float xv2 = xq[0], wt2 = wq[0];
        #pragma unroll 1
        for (int p = 0; p < 4; ++p) {
            #pragma unroll
            for (int j = 0; j < 8; ++j) C1[j] = b2[j * 64];
            b2 += 512;
            const float xv3 = xq[1], wt3 = wq[1];
            {
                short8 a0, a1;
                agen16(wb2, xv2, wt2, a0, a1);
                acc2[0] = __builtin_amdgcn_mfma_f32_16x16x32_bf16(a0, *(short8*)&C0[0], acc2[0], 0, 0, 0);
                acc2[1] = __builtin_amdgcn_mfma_f32_16x16x32_bf16(a0, *(short8*)&C0[1], acc2[1], 0, 0, 0);
                acc2[2] = __builtin_amdgcn_mfma_f32_16x16x32_bf16(a0, *(short8*)&C0[2], acc2[2], 0, 0, 0);
                acc2[3] = __builtin_amdgcn_mfma_f32_16x16x32_bf16(a0, *(short8*)&C0[3], acc2[3], 0, 0, 0);
                acc2[0] = __builtin_amdgcn_mfma_f32_16x16x32_bf16(a1, *(short8*)&C0[4], acc2[0], 0, 0, 0);
                acc2[1] = __builtin_amdgcn_mfma_f32_16x16x32_bf16(a1, *(short8*)&C0[5], acc2[1], 0, 0, 0);
                acc2[2] = __builtin_amdgcn_mfma_f32_16x16x32_bf16(a1, *(short8*)&C0[6], acc2[2], 0, 0, 0);
                acc2[3] = __builtin_amdgcn_mfma_f32_16x16x32_bf16(a1, *(short8*)&C0[7], acc2[3], 0, 0, 0);
            }
            wb2 += 128;
            #pragma unroll
            for (int j = 0; j < 8; ++j) C0[j] = b2[j * 64];
            b2 += 512;
            xv2 = xq[2]; wt2 = wq[2];
            {
                short8 a0, a1;
                agen16(wb2, xv3, wt3, a0, a1);
                acc2[0] = __builtin_amdgcn_mfma_f32_16x16x32_bf16(a0, *(short8*)&C1[0], acc2[0], 0, 0, 0);
                acc2[1] = __builtin_amdgcn_mfma_f32_16x16x32_bf16(a0, *(short8*)&C1[1], acc2[1], 0, 0, 0);
                acc2[2] = __builtin_amdgcn_mfma_f32_16x16x32_bf16(a0, *(short8*)&C1[2], acc2[2], 0, 0, 0);
                acc2[3] = __builtin_amdgcn_mfma_f32_16x16x32_bf16(a0, *(short8*)&C1[3], acc2[3], 0, 0, 0);
                acc2[0] = __builtin_amdgcn_mfma_f32_16x16x32_bf16(a1, *(short8*)&C1[4], acc2[0], 0, 0, 0);
                acc2[1] = __builtin_amdgcn_mfma_f32_16x16x32_bf16(a1, *(short8*)&C1[5], acc2[1], 0, 0, 0);
                acc2[2] = __builtin_amdgcn_mfma_f32_16x16x32_bf16(a1, *(short8*)&C1[6], acc2[2], 0, 0, 0);
                acc2[3] = __builtin_amdgcn_mfma_f32_16x16x32_bf16(a1, *(short8*)&C1[7], acc2[3], 0, 0, 0);
            }
            wb2 += 128; xq += 2; wq += 2;
        }
        #pragma unroll
        for (int u = 0; u < 4; ++u) asm volatile("" :: "v"(acc2[u]));
    }

    // ==== REAL f-loop (v6 structure, agen16 refactor, identical numerics) ====
    f32x4 acc[4];
    #pragma unroll
    for (int u = 0; u < 4; ++u) acc[u] = (f32x4){0.f, 0.f, 0.f, 0.f};

    const uint4* bp = (const uint4*)img + (size_t)f0 * 512 + lane;
    uint4 B0[8], B1[8];
    #pragma unroll
    for (int j = 0; j < 8; ++j) B0[j] = bp[j * 64];
    bp += 512;

    const float* xp    = &xls[trow * 68 + f0];
    const float* wp    = &wls[trow * 68 + f0];
    const float* wbase = &wbped[f0 * 128 + quad * 8];
    float xvA = xp[0], wtA = wp[0];

    #pragma unroll 1
    for (int p = 0; p < 8; ++p) {
        #pragma unroll
        for (int j = 0; j < 8; ++j) B1[j] = bp[j * 64];
        bp += 512;
        const float xvB = xp[1], wtB = wp[1];
        {
            short8 a0, a1;
            agen16(wbase, xvA, wtA, a0, a1);
            acc[0] = __builtin_amdgcn_mfma_f32_16x16x32_bf16(a0, *(short8*)&B0[0], acc[0], 0, 0, 0);
            acc[1] = __builtin_amdgcn_mfma_f32_16x16x32_bf16(a0, *(short8*)&B0[1], acc[1], 0, 0, 0);
            acc[2] = __builtin_amdgcn_mfma_f32_16x16x32_bf16(a0, *(short8*)&B0[2], acc[2], 0, 0, 0);
            acc[3] = __builtin_amdgcn_mfma_f32_16x16x32_bf16(a0, *(short8*)&B0[3], acc[3], 0, 0, 0);
            acc[0] = __builtin_amdgcn_mfma_f32_16x16x32_bf16(a1, *(short8*)&B0[4], acc[0], 0, 0, 0);
            acc[1] = __builtin_amdgcn_mfma_f32_16x16x32_bf16(a1, *(short8*)&B0[5], acc[1], 0, 0, 0);
            acc[2] = __builtin_amdgcn_mfma_f32_16x16x32_bf16(a1, *(short8*)&B0[6], acc[2], 0, 0, 0);
            acc[3] = __builtin_amdgcn_mfma_f32_16x16x32_bf16(a1, *(short8*)&B0[7], acc[3], 0, 0, 0);
        }
        wbase += 128;

        #pragma unroll
        for (int j = 0; j < 8; ++j) B0[j] = bp[j * 64];   // p==7: slot f0+16 (<=64), dead
        bp += 512;
        xvA = xp[2]; wtA = wp[2];                          // p==7: row pad, dead
        {
            short8 a0, a1;
            agen16(wbase, xvB, wtB, a0, a1);
            acc[0] = __builtin_amdgcn_mfma_f32_16x16x32_bf16(a0, *(short8*)&B1[0], acc[0], 0, 0, 0);
            acc[1] = __builtin_amdgcn_mfma_f32_16x16x32_bf16(a0, *(short8*)&B1[1], acc[1], 0, 0, 0);
            acc[2] = __builtin_amdgcn_mfma_f32_16x16x32_bf16(a0, *(short8*)&B1[2], acc[2], 0, 0, 0);
            acc[3] = __builtin_amdgcn_mfma_f32_16x16x32_bf16(a0, *(short8*)&B1[3], acc[3], 0, 0, 0);
            acc[0] = __builtin_amdgcn_mfma_f32_16x16x32_bf16(a1, *(short8*)&B1[4], acc[0], 0, 0, 0);
            acc[1] = __builtin_amdgcn_mfma_f32_16x16x32_bf16(a1, *(short8*)&B1[5], acc[1], 0, 0, 0);
            acc[2] = __builtin_amdgcn_mfma_f32_16x16x32_bf16(a1, *(short8*)&B1[6], acc[2], 0, 0, 0);
            acc[3] = __builtin_amdgcn_mfma_f32_16x16x32_bf16(a1, *(short8*)&B1[7], acc[3], 0, 0, 0);
        }
        wbase += 128; xp += 2; wp += 2;
    }

    // ---- bias K-chunk: waves 0..3 = {eh = g} x {tile} ----
    if (wv < 4) {
        const int eh = g;
        const int e0 = eh * 32 + quad * 8;
        uint4 av;
        av.x = pack_bf16(wls[trow * 68 + e0 + 0], wls[trow * 68 + e0 + 1]);
        av.y = pack_bf16(wls[trow * 68 + e0 + 2], wls[trow * 68 + e0 + 3]);
        av.z = pack_bf16(wls[trow * 68 + e0 + 4], wls[trow * 68 + e0 + 5]);
        av.w = pack_bf16(wls[trow * 68 + e0 + 6], wls[trow * 68 + e0 + 7]);
        const short8 a = *(short8*)&av;
        const uint4* bq = (const uint4*)img + (size_t)64 * 512 + lane;
        #pragma unroll
        for (int u = 0; u < 4; ++u) {
            uint4 bv = bq[eh * 256 + u * 64];
            acc[u] = __builtin_amdgcn_mfma_f32_16x16x32_bf16(a, *(short8*)&bv, acc[u], 0, 0, 0);
        }
    }

    // ---- tail: per tile, reduce 4 wave-partials in wbped ----
    __syncthreads();
    if (g >= 2) {
        float* p = wbped + tile * 2176 + (g - 2) * 1088;
        #pragma unroll
        for (int u = 0; u < 4; ++u)
            #pragma unroll
            for (int r = 0; r < 4; ++r)
                p[(quad * 4 + r) * 68 + u * 16 + m] = acc[u][r];
    }
    __syncthreads();
    if (g < 2) {
        const float* p = wbped + tile * 2176 + g * 1088;
        #pragma unroll
        for (int u = 0; u < 4; ++u)
            #pragma unroll
            for (int r = 0; r < 4; ++r)
                acc[u][r] += p[(quad * 4 + r) * 68 + u * 16 + m];
    }
    __syncthreads();
    if (g == 1) {
        float* p = wbped + tile * 2176;
        #pragma unroll
        for (int u = 0; u < 4; ++u)
            #pragma unroll
            for (int r = 0; r < 4; ++r)
                p[(quad * 4 + r) * 68 + u * 16 + m] = acc[u][r];
    }
    __syncthreads();
    if (g == 0) {
        float* p = wbped + tile * 2176;
        #pragma unroll
        for (int u = 0; u < 4; ++u)
            #pragma unroll
            for (int r = 0; r < 4; ++r) {
                const int idx = (quad * 4 + r) * 68 + u * 16 + m;
                p[idx] += acc[u][r];
            }
    }
    __syncthreads();

    {
        const int t = tid >> 4, kq = tid & 15;
        const float* srcp = wbped + (t >> 4) * 2176 + (t & 15) * 68 + kq * 4;
        *(float4*)(out + (size_t)(tokbase + t) * 64 + kq * 4) = *(const float4*)srcp;
    }
}

// ---------------- DIAGNOSTIC probe: memory path only ----------------
// Exact v6 img-load pattern, 4 reps, zero math. Isolates L1/L2 delivery.
__global__ __launch_bounds__(512, 4)
void probe_mem(const unsigned short* __restrict__ img) {
    const int tid = threadIdx.x;
    const int wv = tid >> 6, lane = tid & 63;
    const int g = wv >> 1;
    const int f0 = g * 16;
    #pragma unroll 1
    for (int rep = 0; rep < 4; ++rep) {
        const uint32x4* bp = (const uint32x4*)img + (size_t)f0 * 512 + lane;
        #pragma unroll 1
        for (int p = 0; p < 16; ++p) {
            uint32x4 B[8];
            #pragma unroll
            for (int j = 0; j < 8; ++j) B[j] = bp[j * 64];
            #pragma unroll
            for (int j = 0; j < 8; ++j) asm volatile("" :: "v"(B[j]));
            bp += 512;
        }
    }
}

// ---------------- DIAGNOSTIC probe: VALU/MFMA/LDS path only ----------------
// Exact staging + A-gen + MFMA + LDS reads, 3 reps, no global loads in loop.
__global__ __launch_bounds__(512, 4)
void probe_valu(const float* __restrict__ x,
                const float* __restrict__ ew1, const float* __restrict__ eb1,
                const unsigned short* __restrict__ img,
                const float* __restrict__ wtg)
{
    __shared__ __align__(16) float xls[32 * 68];
    __shared__ __align__(16) float wls[32 * 68];
    __shared__ __align__(16) float wbped[64 * 128];

    const int tid = threadIdx.x;
    const int wv = tid >> 6, lane = tid & 63;
    const int m = tid & 15, quad = (tid >> 4) & 3;
    const int tile = wv & 1, g = wv >> 1;
    const int f0 = g * 16;
    const int trow = tile * 16 + m;
    const int tokbase = blockIdx.x * 32;

    {
        const int t = tid >> 4, fq = (tid & 15) * 4;
        *(float4*)&xls[t * 68 + fq] =
            *(const float4*)(x + (size_t)(tokbase + t) * 64 + fq);
        *(float4*)&wls[t * 68 + fq] =
            *(const float4*)(wtg + (size_t)(tokbase + t) * 64 + fq);
        #pragma unroll
        for (int k = 0; k < 2; ++k) {
            const int idx = tid + k * 512;
            const int fr = idx >> 4, c4 = (idx & 15) * 4;
            *(float4*)&wbped[fr * 128 + c4]      = *(const float4*)(ew1 + fr * 64 + c4);
            *(float4*)&wbped[fr * 128 + 64 + c4] = *(const float4*)(eb1 + fr * 64 + c4);
        }
    }
    __syncthreads();

    uint4 Bc[8];
    #pragma unroll
    for (int j = 0; j < 8; ++j)
        Bc[j] = ((const uint4*)img)[(size_t)f0 * 512 + j * 64 + lane];

    f32x4 acc[4];
    #pragma unroll
    for (int u = 0; u < 4; ++u) acc[u] = (f32x4){0.f, 0.f, 0.f, 0.f};

    #pragma unroll 1
    for (int rep = 0; rep < 3; ++rep) {
        const float* xq = &xls[trow * 68 + f0];
        const float* wq = &wls[trow * 68 + f0];
        const float* wb2 = &wbped[f0 * 128 + quad * 8];
        #pragma unroll 1
        for (int p = 0; p < 16; ++p) {
            short8 a0, a1;
            agen16(wb2, xq[0], wq[0], a0, a1);
            acc[0] = __builtin_amdgcn_mfma_f32_16x16x32_bf16(a0, *(short8*)&Bc[0], acc[0], 0, 0, 0);
            acc[1] = __builtin_amdgcn_mfma_f32_16x16x32_bf16(a0, *(short8*)&Bc[1], acc[1], 0, 0, 0);
            acc[2] = __builtin_amdgcn_mfma_f32_16x16x32_bf16(a0, *(short8*)&Bc[2], acc[2], 0, 0, 0);
            acc[3] = __builtin_amdgcn_mfma_f32_16x16x32_bf16(a0, *(short8*)&Bc[3], acc[3], 0, 0, 0);
            acc[0] = __builtin_amdgcn_mfma_f32_16x16x32_bf16(a1, *(short8*)&Bc[4], acc[0], 0, 0, 0);
            acc[1] = __builtin_amdgcn_mfma_f32_16x16x32_bf16(a1, *(short8*)&Bc[5], acc[1], 0, 0, 0);
            acc[2] = __builtin_amdgcn_mfma_f32_16x16x32_bf16(a1, *(short8*)&Bc[6], acc[2], 0, 0, 0);
            acc[3] = __builtin_amdgcn_mfma_f32_16x16x32_bf16(a1, *(short8*)&Bc[7], acc[3], 0, 0, 0);
            wb2 += 128; xq += 1; wq += 1;
        }
    }
    #pragma unroll
    for (int u = 0; u < 4; ++u) asm volatile("" :: "v"(acc[u]));
}

// ======================================================================
// Mid-tier (round-0 proven): 512 blocks x 512 thr, gating in-kernel.
// ======================================================================
__global__ __launch_bounds__(512, 4)
void moe_main(const float* __restrict__ x,   const float* __restrict__ s,
              const float* __restrict__ fw1, const float* __restrict__ fb1,
              const float* __restrict__ fw2, const float* __restrict__ fb2,
              const float* __restrict__ fw3, const float* __restrict__ fb3,
              const float* __restrict__ ew1, const float* __restrict__ eb1,
              const float* __restrict__ ew3, const float* __restrict__ eb3,
              const unsigned short* __restrict__ img,
              float* __restrict__ out)
{
    __shared__ __align__(16) float xls[32 * 68];
    __shared__ __align__(16) float wts[32 * 65];
    __shared__ __align__(16) float egs[32 * 64];
    __shared__ __align__(16) float ped0[4][16 * 68];
    __shared__ __align__(16) float ped1[4][16 * 68];

    const int tid = threadIdx.x;
    const int wv = tid >> 6, lane = tid & 63;
    const int m = tid & 15, quad = (tid >> 4) & 3;
    const int tokbase = blockIdx.x * 32;

    {
        const int t = tid >> 4, fq = (tid & 15) * 4;
        *(float4*)&xls[t * 68 + fq] =
            *(const float4*)(x + (size_t)(tokbase + t) * 64 + fq);
    }
    __syncthreads();

    {
        const int t0w = wv * 4;
        const float* sw = s + (size_t)(tokbase + t0w) * 32;
        float g[4];
        const float b0 = fb1[lane] + fb2[lane];
        #pragma unroll
        for (int t = 0; t < 4; ++t) g[t] = b0;
        for (int f = 0; f < 64; f += 4) {
            const float w0 = fw1[(f + 0) * 64 + lane];
            const float w1 = fw1[(f + 1) * 64 + lane];
            const float w2 = fw1[(f + 2) * 64 + lane];
            const float w3v = fw1[(f + 3) * 64 + lane];
            #pragma unroll
            for (int t = 0; t < 4; ++t) {
                const float4 xa = *(const float4*)&xls[(t0w + t) * 68 + f];
                g[t] = fmaf(xa.x, w0, fmaf(xa.y, w1, fmaf(xa.z, w2, fmaf(xa.w, w3v, g[t]))));
            }
        }
        for (int e = 0; e < 32; e += 4) {
            const float w0 = fw2[(e + 0) * 64 + lane];
            const float w1 = fw2[(e + 1) * 64 + lane];
            const float w2 = fw2[(e + 2) * 64 + lane];
            const float w3v = fw2[(e + 3) * 64 + lane];
            #pragma unroll
            for (int t = 0; t < 4; ++t) {
                const float4 sa = *(const float4*)(sw + t * 32 + e);
                g[t] = fmaf(sa.x, w0, fmaf(sa.y, w1, fmaf(sa.z, w2, fmaf(sa.w, w3v, g[t]))));
            }
        }
        #pragma unroll
        for (int t = 0; t < 4; ++t) egs[(t0w + t) * 64 + lane] = eluf(g[t]);

        float lg[4];
        const float b3 = fb3[lane];
        #pragma unroll
        for (int t = 0; t < 4; ++t) lg[t] = b3;
        for (int h = 0; h < 64; h += 4) {
            const float w0 = fw3[(h + 0) * 64 + lane];
            const float w1 = fw3[(h + 1) * 64 + lane];
            const float w2 = fw3[(h + 2) * 64 + lane];
            const float w3v = fw3[(h + 3) * 64 + lane];
            #pragma unroll
            for (int t = 0; t < 4; ++t) {
                const float4 ev = *(const float4*)&egs[(t0w + t) * 64 + h];
                lg[t] = fmaf(ev.x, w0, fmaf(ev.y, w1, fmaf(ev.z, w2, fmaf(ev.w, w3v, lg[t]))));
            }
        }
        #pragma unroll
        for (int t = 0; t < 4; ++t) {
            float mx = lg[t];
            #pragma unroll
            for (int off = 32; off > 0; off >>= 1) mx = fmaxf(mx, __shfl_xor(mx, off));
            const float p = __expf(lg[t] - mx);
            float sm = p;
            #pragma unroll
            for (int off = 32; off > 0; off >>= 1) sm += __shfl_xor(sm, off);
            wts[(t0w + t) * 65 + lane] = p / sm;
        }
    }
    __syncthreads();

    const int f0 = wv * 8;
    f32x4 acc0[4], acc1[4];
    #pragma unroll
    for (int u = 0; u < 4; ++u) {
        acc0[u] = (f32x4){0.f, 0.f, 0.f, 0.f};
        acc1[u] = (f32x4){0.f, 0.f, 0.f, 0.f};
    }

    const uint4* bp = (const uint4*)img + (size_t)f0 * 512 + lane;
    uint4  B[2][8];
    float4 W[2][4];
    float4 Bb[2][4];
    float  XV[2][2];
    float  WT[2][2];

    #pragma unroll
    for (int i = 0; i < 8; ++i) B[0][i] = bp[(i >> 2) * 256 + (i & 3) * 64];
    bp += 512;
    #pragma unroll
    for (int c = 0; c < 2; ++c) {
        W[0][c * 2 + 0]  = *(const float4*)(ew1 + f0 * 64 + c * 32 + quad * 8);
        W[0][c * 2 + 1]  = *(const float4*)(ew1 + f0 * 64 + c * 32 + quad * 8 + 4);
        Bb[0][c * 2 + 0] = *(const float4*)(eb1 + f0 * 64 + c * 32 + quad * 8);
        Bb[0][c * 2 + 1] = *(const float4*)(eb1 + f0 * 64 + c * 32 + quad * 8 + 4);
    }
    XV[0][0] = xls[m * 68 + f0];        WT[0][0] = wts[m * 65 + f0];
    XV[0][1] = xls[(16 + m) * 68 + f0]; WT[0][1] = wts[(16 + m) * 65 + f0];

    #pragma unroll
    for (int ff = 0; ff < 8; ++ff) {
        const int cur = ff & 1, nxt = cur ^ 1;
        if (ff < 7) {
            const int fn = f0 + ff + 1;
            #pragma unroll
            for (int i = 0; i < 8; ++i) B[nxt][i] = bp[(i >> 2) * 256 + (i & 3) * 64];
            bp += 512;
            #pragma unroll
            for (int c = 0; c < 2; ++c) {
                W[nxt][c * 2 + 0]  = *(const float4*)(ew1 + fn * 64 + c * 32 + quad * 8);
                W[nxt][c * 2 + 1]  = *(const float4*)(ew1 + fn * 64 + c * 32 + quad * 8 + 4);
                Bb[nxt][c * 2 + 0] = *(const float4*)(eb1 + fn * 64 + c * 32 + quad * 8);
                Bb[nxt][c * 2 + 1] = *(const float4*)(eb1 + fn * 64 + c * 32 + quad * 8 + 4);
            }
            XV[nxt][0] = xls[m * 68 + fn];        WT[nxt][0] = wts[m * 65 + fn];
            XV[nxt][1] = xls[(16 + m) * 68 + fn]; WT[nxt][1] = wts[(16 + m) * 65 + fn];
        }
        const float xv0 = XV[cur][0], wt0 = WT[cur][0];
        const float xv1 = XV[cur][1], wt1 = WT[cur][1];
        short8 a0[2], a1[2];
        #pragma unroll
        for (int c = 0; c < 2; ++c) {
            const float4 wa = W[cur][c * 2 + 0],  wb = W[cur][c * 2 + 1];
            const float4 ba = Bb[cur][c * 2 + 0], bb = Bb[cur][c * 2 + 1];
            uint4 v0, v1;
            v0.x = pack_bf16(wt0 * eluf(fmaf(xv0, wa.x, ba.x)),
                             wt0 * eluf(fmaf(xv0, wa.y, ba.y)));
            v0.y = pack_bf16(wt0 * eluf(fmaf(xv0, wa.z, ba.z)),
                             wt0 * eluf(fmaf(xv0, wa.w, ba.w)));
            v0.z = pack_bf16(wt0 * eluf(fmaf(xv0, wb.x, bb.x)),
                             wt0 * eluf(fmaf(xv0, wb.y, bb.y)));
            v0.w = pack_bf16(wt0 * eluf(fmaf(xv0, wb.z, bb.z)),
                             wt0 * eluf(fmaf(xv0, wb.w, bb.w)));
            v1.x = pack_bf16(wt1 * eluf(fmaf(xv1, wa.x, ba.x)),
                             wt1 * eluf(fmaf(xv1, wa.y, ba.y)));
            v1.y = pack_bf16(wt1 * eluf(fmaf(xv1, wa.z, ba.z)),
                             wt1 * eluf(fmaf(xv1, wa.w, ba.w)));
            v1.z = pack_bf16(wt1 * eluf(fmaf(xv1, wb.x, bb.x)),
                             wt1 * eluf(fmaf(xv1, wb.y, bb.y)));
            v1.w = pack_bf16(wt1 * eluf(fmaf(xv1, wb.z, bb.z)),
                             wt1 * eluf(fmaf(xv1, wb.w, bb.w)));
            a0[c] = *(short8*)&v0;
            a1[c] = *(short8*)&v1;
        }
        acc0[0] = __builtin_amdgcn_mfma_f32_16x16x32_bf16(a0[0], *(short8*)&B[cur][0], acc0[0], 0, 0, 0);
        acc0[1] = __builtin_amdgcn_mfma_f32_16x16x32_bf16(a0[0], *(short8*)&B[cur][1], acc0[1], 0, 0, 0);
        acc0[2] = __builtin_amdgcn_mfma_f32_16x16x32_bf16(a0[0], *(short8*)&B[cur][2], acc0[2], 0, 0, 0);
        acc0[3] = __builtin_amdgcn_mfma_f32_16x16x32_bf16(a0[0], *(short8*)&B[cur][3], acc0[3], 0, 0, 0);
        acc1[0] = __builtin_amdgcn_mfma_f32_16x16x32_bf16(a1[0], *(short8*)&B[cur][0], acc1[0], 0, 0, 0);
        acc1[1] = __builtin_amdgcn_mfma_f32_16x16x32_bf16(a1[0], *(short8*)&B[cur][1], acc1[1], 0, 0, 0);
        acc1[2] = __builtin_amdgcn_mfma_f32_16x16x32_bf16(a1[0], *(short8*)&B[cur][2], acc1[2], 0, 0, 0);
        acc1[3] = __builtin_amdgcn_mfma_f32_16x16x32_bf16(a1[0], *(short8*)&B[cur][3], acc1[3], 0, 0, 0);
        acc0[0] = __builtin_amdgcn_mfma_f32_16x16x32_bf16(a0[1], *(short8*)&B[cur][4], acc0[0], 0, 0, 0);
        acc0[1] = __builtin_amdgcn_mfma_f32_16x16x32_bf16(a0[1], *(short8*)&B[cur][5], acc0[1], 0, 0, 0);
        acc0[2] = __builtin_amdgcn_mfma_f32_16x16x32_bf16(a0[1], *(short8*)&B[cur][6], acc0[2], 0, 0, 0);
        acc0[3] = __builtin_amdgcn_mfma_f32_16x16x32_bf16(a0[1], *(short8*)&B[cur][7], acc0[3], 0, 0, 0);
        acc1[0] = __builtin_amdgcn_mfma_f32_16x16x32_bf16(a1[1], *(short8*)&B[cur][4], acc1[0], 0, 0, 0);
        acc1[1] = __builtin_amdgcn_mfma_f32_16x16x32_bf16(a1[1], *(short8*)&B[cur][5], acc1[1], 0, 0, 0);
        acc1[2] = __builtin_amdgcn_mfma_f32_16x16x32_bf16(a1[1], *(short8*)&B[cur][6], acc1[2], 0, 0, 0);
        acc1[3] = __builtin_amdgcn_mfma_f32_16x16x32_bf16(a1[1], *(short8*)&B[cur][7], acc1[3], 0, 0, 0);
    }

    if (wv < 4) {
        const int tile = wv >> 1, eh = wv & 1;
        const int e0 = eh * 32 + quad * 8;
        const int trow = tile * 16 + m;
        uint4 av;
        av.x = pack_bf16(wts[trow * 65 + e0 + 0], wts[trow * 65 + e0 + 1]);
        av.y = pack_bf16(wts[trow * 65 + e0 + 2], wts[trow * 65 + e0 + 3]);
        av.z = pack_bf16(wts[trow * 65 + e0 + 4], wts[trow * 65 + e0 + 5]);
        av.w = pack_bf16(wts[trow * 65 + e0 + 6], wts[trow * 65 + e0 + 7]);
        short8 a = *(short8*)&av;
        const uint4* bq = (const uint4*)img + (size_t)64 * 512;
        if (tile == 0) {
            #pragma unroll
            for (int u = 0; u < 4; ++u) {
                uint4 bv = bq[eh * 256 + u * 64 + lane];
                acc0[u] = __builtin_amdgcn_mfma_f32_16x16x32_bf16(a, *(short8*)&bv, acc0[u], 0, 0, 0);
            }
        } else {
            #pragma unroll
            for (int u = 0; u < 4; ++u) {
                uint4 bv = bq[eh * 256 + u * 64 + lane];
                acc1[u] = __builtin_amdgcn_mfma_f32_16x16x32_bf16(a, *(short8*)&bv, acc1[u], 0, 0, 0);
            }
        }
    }

    if (wv >= 4) {
        #pragma unroll
        for (int u = 0; u < 4; ++u)
            #pragma unroll
            for (int r = 0; r < 4; ++r) {
                const int idx = (quad * 4 + r) * 68 + u * 16 + m;
                ped0[wv - 4][idx] = acc0[u][r];
                ped1[wv - 4][idx] = acc1[u][r];
            }
    }
    __syncthreads();
    if (wv < 4) {
        #pragma unroll
        for (int u = 0; u < 4; ++u)
            #pragma unroll
            for (int r = 0; r < 4; ++r) {
                const int idx = (quad * 4 + r) * 68 + u * 16 + m;
                acc0[u][r] += ped0[wv][idx];
                acc1[u][r] += ped1[wv][idx];
            }
    }
    __syncthreads();
    if (wv == 2 || wv == 3) {
        #pragma unroll
        for (int u = 0; u < 4; ++u)
            #pragma unroll
            for (int r = 0; r < 4; ++r) {
                const int idx = (quad * 4 + r) * 68 + u * 16 + m;
                ped0[wv - 2][idx] = acc0[u][r];
                ped1[wv - 2][idx] = acc1[u][r];
            }
    }
    __syncthreads();
    if (wv < 2) {
        #pragma unroll
        for (int u = 0; u < 4; ++u)
            #pragma unroll
            for (int r = 0; r < 4; ++r) {
                const int idx = (quad * 4 + r) * 68 + u * 16 + m;
                acc0[u][r] += ped0[wv][idx];
                acc1[u][r] += ped1[wv][idx];
            }
    }
    __syncthreads();
    if (wv == 1) {
        #pragma unroll
        for (int u = 0; u < 4; ++u)
            #pragma unroll
            for (int r = 0; r < 4; ++r) {
                const int idx = (quad * 4 + r) * 68 + u * 16 + m;
                ped0[0][idx] = acc0[u][r];
                ped1[0][idx] = acc1[u][r];
            }
    }
    __syncthreads();
    if (wv == 0) {
        #pragma unroll
        for (int u = 0; u < 4; ++u)
            #pragma unroll
            for (int r = 0; r < 4; ++r) {
                const int idx = (quad * 4 + r) * 68 + u * 16 + m;
                ped0[0][idx] += acc0[u][r];
                ped1[0][idx] += acc1[u][r];
            }
    }
    __syncthreads();

    {
        const int t = tid >> 4, kq = tid & 15;
        const float* srcp = (t < 16) ? &ped0[0][t * 68 + kq * 4]
                                     : &ped1[0][(t - 16) * 68 + kq * 4];
        *(float4*)(out + (size_t)(tokbase + t) * 64 + kq * 4) = *(const float4*)srcp;
    }
}

// ======================================================================
// Fallback (ws-free), validated structure: 1024 blocks x 512 thr, 16 tok
// ======================================================================
__device__ __forceinline__ void gen_a_fb(const float* __restrict__ ew1,
                                         const float* __restrict__ eb1,
                                         int f, int quad, float xv, float wt,
                                         short8* a) {
    #pragma unroll
    for (int c = 0; c < 2; ++c) {
        const float* w1p = ew1 + f * 64 + c * 32 + quad * 8;
        const float* b1p = eb1 + f * 64 + c * 32 + quad * 8;
        const float4 w1a = *(const float4*)w1p, w1b = *(const float4*)(w1p + 4);
        const float4 b1a = *(const float4*)b1p, b1b = *(const float4*)(b1p + 4);
        uint4 av;
        av.x = pack_bf16(wt * eluf(fmaf(xv, w1a.x, b1a.x)),
                         wt * eluf(fmaf(xv, w1a.y, b1a.y)));
        av.y = pack_bf16(wt * eluf(fmaf(xv, w1a.z, b1a.z)),
                         wt * eluf(fmaf(xv, w1a.w, b1a.w)));
        av.z = pack_bf16(wt * eluf(fmaf(xv, w1b.x, b1b.x)),
                         wt * eluf(fmaf(xv, w1b.y, b1b.y)));
        av.w = pack_bf16(wt * eluf(fmaf(xv, w1b.z, b1b.z)),
                         wt * eluf(fmaf(xv, w1b.w, b1b.w)));
        a[c] = *(short8*)&av;
    }
}
__device__ __forceinline__ void gen_b_fp32(const float* __restrict__ w3f,
                                           int quad, int m, short8 b[2][4]) {
    #pragma unroll
    for (int c = 0; c < 2; ++c)
        #pragma unroll
        for (int u = 0; u < 4; ++u) {
            const float* wp = w3f + (size_t)(c * 32 + quad * 8) * 64 + u * 16 + m;
            uint4 v;
            v.x = pack_bf16(wp[0],   wp[64]);
            v.y = pack_bf16(wp[128], wp[192]);
            v.z = pack_bf16(wp[256], wp[320]);
            v.w = pack_bf16(wp[384], wp[448]);
            b[c][u] = *(short8*)&v;
        }
}

__global__ __launch_bounds__(512, 8)
void moe_fb(const float* __restrict__ x,   const float* __restrict__ s,
            const float* __restrict__ fw1, const float* __restrict__ fb1,
            const float* __restrict__ fw2, const float* __restrict__ fb2,
            const float* __restrict__ fw3, const float* __restrict__ fb3,
            const float* __restrict__ ew1, const float* __restrict__ eb1,
            const float* __restrict__ ew3, const float* __restrict__ eb3,
            float* __restrict__ out)
{
    __shared__ __align__(16) float xls[16 * 68];
    __shared__ __align__(16) float wts[16 * 65];
    __shared__ __align__(16) float egs[16 * 64];
    __shared__ __align__(16) float ped[4][16 * 68];

    const int tid = threadIdx.x;
    const int wv = tid >> 6, lane = tid & 63;
    const int tokbase = blockIdx.x * 16;

    if (tid < 256) {
        const int t = tid >> 4, fq = (tid & 15) * 4;
        *(float4*)&xls[t * 68 + fq] =
            *(const float4*)(x + (size_t)(tokbase + t) * 64 + fq);
    }
    __syncthreads();
    {
        const int t0w = wv * 2;
        const float* sw = s + (size_t)(tokbase + t0w) * 32;
        float g0, g1;
        g0 = g1 = fb1[lane] + fb2[lane];
        for (int ff = 0; ff < 64; ff += 4) {
            const float4 xa = *(const float4*)&xls[(t0w + 0) * 68 + ff];
            const float4 xb = *(const float4*)&xls[(t0w + 1) * 68 + ff];
            const float w0 = fw1[(ff + 0) * 64 + lane];
            const float w1 = fw1[(ff + 1) * 64 + lane];
            const float w2 = fw1[(ff + 2) * 64 + lane];
            const float w3v = fw1[(ff + 3) * 64 + lane];
            g0 = fmaf(xa.x, w0, fmaf(xa.y, w1, fmaf(xa.z, w2, fmaf(xa.w, w3v, g0))));
            g1 = fmaf(xb.x, w0, fmaf(xb.y, w1, fmaf(xb.z, w2, fmaf(xb.w, w3v, g1))));
        }
        for (int e = 0; e < 32; e += 4) {
            const float4 sa = *(const float4*)(sw + e);
            const float4 sb = *(const float4*)(sw + 32 + e);
            const float w0 = fw2[(e + 0) * 64 + lane];
            const float w1 = fw2[(e + 1) * 64 + lane];
            const float w2 = fw2[(e + 2) * 64 + lane];
            const float w3v = fw2[(e + 3) * 64 + lane];
            g0 = fmaf(sa.x, w0, fmaf(sa.y, w1, fmaf(sa.z, w2, fmaf(sa.w, w3v, g0))));
            g1 = fmaf(sb.x, w0, fmaf(sb.y, w1, fmaf(sb.z, w2, fmaf(sb.w, w3v, g1))));
        }
        egs[(t0w + 0) * 64 + lane] = eluf(g0);
        egs[(t0w + 1) * 64 + lane] = eluf(g1);
        float lg0 = fb3[lane], lg1 = lg0;
        for (int h = 0; h < 64; h += 4) {
            const float4 e0 = *(const float4*)&egs[(t0w + 0) * 64 + h];
            const float4 e1 = *(const float4*)&egs[(t0w + 1) * 64 + h];
            const float w0 = fw3[(h + 0) * 64 + lane];
            const float w1 = fw3[(h + 1) * 64 + lane];
            const float w2 = fw3[(h + 2) * 64 + lane];
            const float w3v = fw3[(h + 3) * 64 + lane];
            lg0 = fmaf(e0.x, w0, fmaf(e0.y, w1, fmaf(e0.z, w2, fmaf(e0.w, w3v, lg0))));
            lg1 = fmaf(e1.x, w0, fmaf(e1.y, w1, fmaf(e1.z, w2, fmaf(e1.w, w3v, lg1))));
        }
        float mx0 = lg0, mx1 = lg1;
        #pragma unroll
        for (int off = 32; off > 0; off >>= 1) {
            mx0 = fmaxf(mx0, __shfl_xor(mx0, off));
            mx1 = fmaxf(mx1, __shfl_xor(mx1, off));
        }
        const float p0 = __expf(lg0 - mx0), p1 = __expf(lg1 - mx1);
        float s0 = p0, s1 = p1;
        #pragma unroll
        for (int off = 32; off > 0; off >>= 1) {
            s0 += __shfl_xor(s0, off);
            s1 += __shfl_xor(s1, off);
        }
        wts[(t0w + 0) * 65 + lane] = p0 / s0;
        wts[(t0w + 1) * 65 + lane] = p1 / s1;
    }
    __syncthreads();

    const int m = tid & 15, quad = (tid >> 4) & 3;
    const int f0 = wv * 8;
    f32x4 acc[4];
    #pragma unroll
    for (int u = 0; u < 4; ++u) acc[u] = (f32x4){0.f, 0.f, 0.f, 0.f};

    #pragma unroll
    for (int ff = 0; ff < 8; ++ff) {
        const int fcur = f0 + ff;
        short8 b[2][4], a[2];
        gen_b_fp32(ew3 + (size_t)fcur * 4096, quad, m, b);
        gen_a_fb(ew1, eb1, fcur, quad, xls[m * 68 + fcur], wts[m * 65 + fcur], a);
        #pragma unroll
        for (int u = 0; u < 4; ++u) {
            acc[u] = __builtin_amdgcn_mfma_f32_16x16x32_bf16(a[0], b[0][u], acc[u], 0, 0, 0);
            acc[u] = __builtin_amdgcn_mfma_f32_16x16x32_bf16(a[1], b[1][u], acc[u], 0, 0, 0);
        }
    }
    if (wv < 2) {
        const int e0 = wv * 32 + quad * 8;
        uint4 av;
        av.x = pack_bf16(wts[m * 65 + e0 + 0], wts[m * 65 + e0 + 1]);
        av.y = pack_bf16(wts[m * 65 + e0 + 2], wts[m * 65 + e0 + 3]);
        av.z = pack_bf16(wts[m * 65 + e0 + 4], wts[m * 65 + e0 + 5]);
        av.w = pack_bf16(wts[m * 65 + e0 + 6], wts[m * 65 + e0 + 7]);
        short8 a = *(short8*)&av;
        #pragma unroll
        for (int u = 0; u < 4; ++u) {
            const float* wp = eb3 + (size_t)e0 * 64 + u * 16 + m;
            uint4 bv;
            bv.x = pack_bf16(wp[0],   wp[64]);
            bv.y = pack_bf16(wp[128], wp[192]);
            bv.z = pack_bf16(wp[256], wp[320]);
            bv.w = pack_bf16(wp[384], wp[448]);
            acc[u] = __builtin_amdgcn_mfma_f32_16x16x32_bf16(a, *(short8*)&bv, acc[u], 0, 0, 0);
        }
    }
    if (wv >= 4) {
        #pragma unroll
        for (int u = 0; u < 4; ++u)
            #pragma unroll
            for (int r = 0; r < 4; ++r)
                ped[wv - 4][(quad * 4 + r) * 68 + u * 16 + m] = acc[u][r];
    }
    __syncthreads();
    if (wv < 4) {
        #pragma unroll
        for (int u = 0; u < 4; ++u)
            #pragma unroll
            for (int r = 0; r < 4; ++r)
                acc[u][r] += ped[wv][(quad * 4 + r) * 68 + u * 16 + m];
    }
    __syncthreads();
    if (wv == 2 || wv == 3) {
        #pragma unroll
        for (int u = 0; u < 4; ++u)
            #pragma unroll
            for (int r = 0; r < 4; ++r)
                ped[wv - 2][(quad * 4 + r) * 68 + u * 16 + m] = acc[u][r];
    }
    __syncthreads();
    if (wv < 2) {
        #pragma unroll
        for (int u = 0; u < 4; ++u)
            #pragma unroll
            for (int r = 0; r < 4; ++r)
                acc[u][r] += ped[wv][(quad * 4 + r) * 68 + u * 16 + m];
    }
    __syncthreads();
    if (wv == 1) {
        #pragma unroll
        for (int u = 0; u < 4; ++u)
            #pragma unroll
            for (int r = 0; r < 4; ++r)
                ped[0][(quad * 4 + r) * 68 + u * 16 + m] = acc[u][r];
    }
    __syncthreads();
    if (wv == 0) {
        #pragma unroll
        for (int u = 0; u < 4; ++u)
            #pragma unroll
            for (int r = 0; r < 4; ++r)
                ped[0][(quad * 4 + r) * 68 + u * 16 + m] += acc[u][r];
    }
    __syncthreads();
    if (tid < 256) {
        const int t = tid >> 4, kq = tid & 15;
        float4 o = *(const float4*)&ped[0][t * 68 + kq * 4];
        *(float4*)(out + (size_t)(tokbase + t) * 64 + kq * 4) = o;
    }
}

extern "C" void kernel_launch(void* const* d_in, const int* in_sizes, int n_in,
                              void* d_out, int out_size, void* d_ws, size_t ws_size,
                              hipStream_t stream) {
    const float* x   = (const float*)d_in[0];
    const float* s   = (const float*)d_in[1];
    const float* fw1 = (const float*)d_in[2];
    const float* fb1 = (const float*)d_in[3];
    const float* fw2 = (const float*)d_in[4];
    const float* fb2 = (const float*)d_in[5];
    const float* fw3 = (const float*)d_in[6];
    const float* fb3 = (const float*)d_in[7];
    const float* ew1 = (const float*)d_in[8];
    const float* eb1 = (const float*)d_in[9];
    const float* ew3 = (const float*)d_in[10];
    const float* eb3 = (const float*)d_in[11];
    float* out = (float*)d_out;

    const size_t img_bytes = (size_t)65 * 4096 * sizeof(unsigned short); // 532,480
    const size_t wt_bytes  = (size_t)NTOK * 64 * sizeof(float);          // 4,194,304
    const bool al16 = (((uintptr_t)d_ws & 15) == 0);

    if (ws_size >= img_bytes + wt_bytes && al16) {
        unsigned short* img = (unsigned short*)d_ws;
        float* wtg = (float*)((char*)d_ws + img_bytes);
        prep_gate<<<dim3(65 + NTOK / 16), dim3(256), 0, stream>>>(
            ew3, eb3, x, s, fw1, fb1, fw2, fb2, fw3, fb3, img, wtg);
        moe_main7<<<dim3(NTOK / 32), dim3(512), 0, stream>>>(
            x, ew1, eb1, img, wtg, out);
        // DIAGNOSTIC probes (dead outputs, counters only) — removed next round.
        probe_mem<<<dim3(512), dim3(512), 0, stream>>>(img);
        probe_valu<<<dim3(512), dim3(512), 0, stream>>>(x, ew1, eb1, img, wtg);
    } else if (ws_size >= img_bytes && al16) {
        unsigned short* img = (unsigned short*)d_ws;
        prepass<<<dim3(65), dim3(256), 0, stream>>>(ew3, eb3, img);
        moe_main<<<dim3(NTOK / 32), dim3(512), 0, stream>>>(
            x, s, fw1, fb1, fw2, fb2, fw3, fb3, ew1, eb1, ew3, eb3, img, out);
    } else {
        moe_fb<<<dim3(NTOK / 16), dim3(512), 0, stream>>>(
            x, s, fw1, fb1, fw2, fb2, fw3, fb3, ew1, eb1, ew3, eb3, out);
    }
}

// Round 7
// 112.918 us; speedup vs baseline: 2.1900x; 2.1900x over previous
//
#include <hip/hip_runtime.h>
#include <hip/hip_bf16.h>
#include <math.h>

// B=32,T=512 -> NTOK=16384 tokens; F=64; H=64; E=32
#define NTOK 16384
#define LOG2E 1.44269504088896340736f
#define LN2   0.69314718055994530942f

typedef __attribute__((ext_vector_type(8))) short short8;   // 8 bf16 (MFMA A/B)
typedef __attribute__((ext_vector_type(4))) float f32x4;    // MFMA acc

__device__ __forceinline__ unsigned pack_bf16(float a, float b) {
    union { __hip_bfloat162 h; unsigned u; } cv;
    cv.h = __float22bfloat162_rn(make_float2(a, b));
    return cv.u;
}
// HW pack: v_cvt_pk_bf16_f32 (RNE, same as _rn for finite values). T12 recipe.
__device__ __forceinline__ unsigned pk_bf16(float a, float b) {
    unsigned r;
    asm("v_cvt_pk_bf16_f32 %0, %1, %2" : "=v"(r) : "v"(a), "v"(b));
    return r;
}
__device__ __forceinline__ float exp2_hw(float x) {
#if __has_builtin(__builtin_amdgcn_exp2f)
    return __builtin_amdgcn_exp2f(x);
#else
    return __expf(x * LN2);
#endif
}
__device__ __forceinline__ float eluf(float z) {
    return z > 0.0f ? z : (__expf(z) - 1.0f);
}

// Trimmed A-gen for one f: weights/biases PRE-SCALED by LOG2E in LDS.
// Per site: fmaf + min + max + exp2(trans) + 2 fma  (5 VALU + 1 T), then
// HW cvt_pk per pair. o = wt*elu(z) exactly (positive branch: inner fma
// yields wt*1-wt = +0 exactly; negative: zp=0 passes s through).
__device__ __forceinline__ void agen16t(const float* __restrict__ wb,
                                        float xv, float wt, float wtln2,
                                        short8& A0, short8& A1) {
    auto site = [&](float w, float b) -> float {
        const float z2 = fmaf(xv, w, b);                    // z * log2e
        const float e  = exp2_hw(fminf(z2, 0.0f));          // exp(min(z,0))
        return fmaf(wtln2, fmaxf(z2, 0.0f), fmaf(wt, e, -wt));
    };
    {
        const float4 wa  = *(const float4*)(wb);
        const float4 wv2 = *(const float4*)(wb + 4);
        const float4 ba  = *(const float4*)(wb + 64);
        const float4 bb  = *(const float4*)(wb + 68);
        uint4 v0;
        v0.x = pk_bf16(site(wa.x,  ba.x), site(wa.y,  ba.y));
        v0.y = pk_bf16(site(wa.z,  ba.z), site(wa.w,  ba.w));
        v0.z = pk_bf16(site(wv2.x, bb.x), site(wv2.y, bb.y));
        v0.w = pk_bf16(site(wv2.z, bb.z), site(wv2.w, bb.w));
        A0 = *(short8*)&v0;
    }
    {
        const float4 wc = *(const float4*)(wb + 32);
        const float4 wd = *(const float4*)(wb + 36);
        const float4 bc = *(const float4*)(wb + 96);
        const float4 bd = *(const float4*)(wb + 100);
        uint4 v1;
        v1.x = pk_bf16(site(wc.x, bc.x), site(wc.y, bc.y));
        v1.y = pk_bf16(site(wc.z, bc.z), site(wc.w, bc.w));
        v1.z = pk_bf16(site(wd.x, bd.x), site(wd.y, bd.y));
        v1.w = pk_bf16(site(wd.z, bd.z), site(wd.w, bd.w));
        A1 = *(short8*)&v1;
    }
}

// ---------------- prepass: fragment-major bf16 B images ----------------
__global__ __launch_bounds__(256)
void prepass(const float* __restrict__ ew3, const float* __restrict__ eb3,
             unsigned short* __restrict__ ws) {
    __shared__ float tile[64 * 65];
    const int bid = blockIdx.x, tid = threadIdx.x;
    const float* src = (bid < 64) ? (ew3 + (size_t)bid * 4096) : eb3;

    const int r = tid >> 2, c0 = (tid & 3) * 16;
    #pragma unroll
    for (int j = 0; j < 4; ++j) {
        float4 v = *(const float4*)(src + r * 64 + c0 + j * 4);
        tile[r * 65 + c0 + j * 4 + 0] = v.x;
        tile[r * 65 + c0 + j * 4 + 1] = v.y;
        tile[r * 65 + c0 + j * 4 + 2] = v.z;
        tile[r * 65 + c0 + j * 4 + 3] = v.w;
    }
    __syncthreads();

    uint4* dst = (uint4*)(ws + (size_t)bid * 4096);
    #pragma unroll
    for (int it = 0; it < 2; ++it) {
        const int idx = tid + it * 256;
        const int c = idx >> 8, u = (idx >> 6) & 3, l = idx & 63;
        const int mm = l & 15, q = (l >> 4) & 3;
        const int rb = c * 32 + q * 8, col = u * 16 + mm;
        unsigned pw[4];
        #pragma unroll
        for (int p = 0; p < 4; ++p)
            pw[p] = pack_bf16(tile[(rb + 2 * p) * 65 + col],
                              tile[(rb + 2 * p + 1) * 65 + col]);
        uint4 pk; pk.x = pw[0]; pk.y = pw[1]; pk.z = pw[2]; pk.w = pw[3];
        dst[idx] = pk;
    }
}

// ---------------- fused prepass + gating kernel ----------------
__global__ __launch_bounds__(256)
void prep_gate(const float* __restrict__ ew3, const float* __restrict__ eb3,
               const float* __restrict__ x,   const float* __restrict__ s,
               const float* __restrict__ fw1, const float* __restrict__ fb1,
               const float* __restrict__ fw2, const float* __restrict__ fb2,
               const float* __restrict__ fw3, const float* __restrict__ fb3,
               unsigned short* __restrict__ img, float* __restrict__ wtg)
{
    __shared__ float smem[64 * 65];
    const int tid = threadIdx.x;

    if (blockIdx.x < 65) {
        const int bid = blockIdx.x;
        const float* src = (bid < 64) ? (ew3 + (size_t)bid * 4096) : eb3;
        const int r = tid >> 2, c0 = (tid & 3) * 16;
        #pragma unroll
        for (int j = 0; j < 4; ++j) {
            float4 v = *(const float4*)(src + r * 64 + c0 + j * 4);
            smem[r * 65 + c0 + j * 4 + 0] = v.x;
            smem[r * 65 + c0 + j * 4 + 1] = v.y;
            smem[r * 65 + c0 + j * 4 + 2] = v.z;
            smem[r * 65 + c0 + j * 4 + 3] = v.w;
        }
        __syncthreads();
        uint4* dst = (uint4*)(img + (size_t)bid * 4096);
        #pragma unroll
        for (int it = 0; it < 2; ++it) {
            const int idx = tid + it * 256;
            const int c = idx >> 8, u = (idx >> 6) & 3, l = idx & 63;
            const int mm = l & 15, q = (l >> 4) & 3;
            const int rb = c * 32 + q * 8, col = u * 16 + mm;
            unsigned pw[4];
            #pragma unroll
            for (int p = 0; p < 4; ++p)
                pw[p] = pack_bf16(smem[(rb + 2 * p) * 65 + col],
                                  smem[(rb + 2 * p + 1) * 65 + col]);
            uint4 pk; pk.x = pw[0]; pk.y = pw[1]; pk.z = pw[2]; pk.w = pw[3];
            dst[idx] = pk;
        }
        return;
    }

    float* xls = smem;                 // [16][68]
    float* egs = smem + 16 * 68;       // [16][64]
    const int gb = blockIdx.x - 65;
    const int tokbase = gb * 16;
    const int wv = tid >> 6, lane = tid & 63;

    {
        const int t = tid >> 4, fq = (tid & 15) * 4;
        *(float4*)&xls[t * 68 + fq] =
            *(const float4*)(x + (size_t)(tokbase + t) * 64 + fq);
    }
    __syncthreads();

    const int t0w = wv * 4;
    const float* sw = s + (size_t)(tokbase + t0w) * 32;
    float g[4];
    const float b0 = fb1[lane] + fb2[lane];
    #pragma unroll
    for (int t = 0; t < 4; ++t) g[t] = b0;
    #pragma unroll 2
    for (int f = 0; f < 64; f += 4) {
        const float w0 = fw1[(f + 0) * 64 + lane];
        const float w1 = fw1[(f + 1) * 64 + lane];
        const float w2 = fw1[(f + 2) * 64 + lane];
        const float w3v = fw1[(f + 3) * 64 + lane];
        #pragma unroll
        for (int t = 0; t < 4; ++t) {
            const float4 xa = *(const float4*)&xls[(t0w + t) * 68 + f];
            g[t] = fmaf(xa.x, w0, fmaf(xa.y, w1, fmaf(xa.z, w2, fmaf(xa.w, w3v, g[t]))));
        }
    }
    #pragma unroll 2
    for (int e = 0; e < 32; e += 4) {
        const float w0 = fw2[(e + 0) * 64 + lane];
        const float w1 = fw2[(e + 1) * 64 + lane];
        const float w2 = fw2[(e + 2) * 64 + lane];
        const float w3v = fw2[(e + 3) * 64 + lane];
        #pragma unroll
        for (int t = 0; t < 4; ++t) {
            const float4 sa = *(const float4*)(sw + t * 32 + e);
            g[t] = fmaf(sa.x, w0, fmaf(sa.y, w1, fmaf(sa.z, w2, fmaf(sa.w, w3v, g[t]))));
        }
    }
    #pragma unroll
    for (int t = 0; t < 4; ++t) egs[(t0w + t) * 64 + lane] = eluf(g[t]);

    float lg[4];
    const float b3 = fb3[lane];
    #pragma unroll
    for (int t = 0; t < 4; ++t) lg[t] = b3;
    #pragma unroll 2
    for (int h = 0; h < 64; h += 4) {
        const float w0 = fw3[(h + 0) * 64 + lane];
        const float w1 = fw3[(h + 1) * 64 + lane];
        const float w2 = fw3[(h + 2) * 64 + lane];
        const float w3v = fw3[(h + 3) * 64 + lane];
        #pragma unroll
        for (int t = 0; t < 4; ++t) {
            const float4 ev = *(const float4*)&egs[(t0w + t) * 64 + h];
            lg[t] = fmaf(ev.x, w0, fmaf(ev.y, w1, fmaf(ev.z, w2, fmaf(ev.w, w3v, lg[t]))));
        }
    }
    #pragma unroll
    for (int t = 0; t < 4; ++t) {
        float mx = lg[t];
        #pragma unroll
        for (int off = 32; off > 0; off >>= 1) mx = fmaxf(mx, __shfl_xor(mx, off));
        const float p = __expf(lg[t] - mx);
        float sm = p;
        #pragma unroll
        for (int off = 32; off > 0; off >>= 1) sm += __shfl_xor(sm, off);
        wtg[(size_t)(tokbase + t0w + t) * 64 + lane] = p / sm;
    }
}

// ---------------- main kernel v8: v6 structure + VALU-trimmed A-gen ----------------
// 512 blocks x 512 thr. Wave wv: tile = wv&1 (16 tokens), g = wv>>1 (16 f).
// ew1/eb1 staged in LDS PRE-SCALED by LOG2E (saves the per-site ln2 mul);
// A-gen via branch-free min/max elu + hw v_cvt_pk_bf16_f32 (~8 ops/site vs ~20).
// Rolled loop (1.5 KB body), B-fragment ping-pong, identical MFMA order to v6.
__global__ __launch_bounds__(512, 4)
void moe_main8(const float* __restrict__ x,
               const float* __restrict__ ew1, const float* __restrict__ eb1,
               const unsigned short* __restrict__ img,
               const float* __restrict__ wtg,
               float* __restrict__ out)
{
    __shared__ __align__(16) float xls[32 * 68];      // x tile  [t][f]    8704 B
    __shared__ __align__(16) float wls[32 * 68];      // gates   [t][f]    8704 B
    __shared__ __align__(16) float wbped[64 * 128];   // [f][ew1'(64)|eb1'(64)] / tail scratch

    const int tid = threadIdx.x;
    const int wv = tid >> 6, lane = tid & 63;
    const int m = tid & 15, quad = (tid >> 4) & 3;
    const int tile = wv & 1, g = wv >> 1;
    const int f0 = g * 16;
    const int trow = tile * 16 + m;
    const int tokbase = blockIdx.x * 32;

    // ---- stage x, gates + PRE-SCALED ew1/eb1 ----
    {
        const int t = tid >> 4, fq = (tid & 15) * 4;
        *(float4*)&xls[t * 68 + fq] =
            *(const float4*)(x + (size_t)(tokbase + t) * 64 + fq);
        *(float4*)&wls[t * 68 + fq] =
            *(const float4*)(wtg + (size_t)(tokbase + t) * 64 + fq);
        #pragma unroll
        for (int k = 0; k < 2; ++k) {
            const int idx = tid + k * 512;            // 0..1023
            const int fr = idx >> 4, c4 = (idx & 15) * 4;
            float4 wv4 = *(const float4*)(ew1 + fr * 64 + c4);
            float4 bv4 = *(const float4*)(eb1 + fr * 64 + c4);
            wv4.x *= LOG2E; wv4.y *= LOG2E; wv4.z *= LOG2E; wv4.w *= LOG2E;
            bv4.x *= LOG2E; bv4.y *= LOG2E; bv4.z *= LOG2E; bv4.w *= LOG2E;
            *(float4*)&wbped[fr * 128 + c4]      = wv4;
            *(float4*)&wbped[fr * 128 + 64 + c4] = bv4;
        }
    }
    __syncthreads();

    f32x4 acc[4];
    #pragma unroll
    for (int u = 0; u < 4; ++u) acc[u] = (f32x4){0.f, 0.f, 0.f, 0.f};

    // B-fragment j of slot f lives at img_u4[f*512 + j*64 + lane], j = 0..7
    const uint4* bp = (const uint4*)img + (size_t)f0 * 512 + lane;
    uint4 B0[8], B1[8];                // ping-pong, all indices compile-time
    #pragma unroll
    for (int j = 0; j < 8; ++j) B0[j] = bp[j * 64];
    bp += 512;

    const float* xp    = &xls[trow * 68 + f0];
    const float* wp    = &wls[trow * 68 + f0];
    const float* wbase = &wbped[f0 * 128 + quad * 8];
    float xvA = xp[0], wtA = wp[0], wlA = wtA * LN2;

    #pragma unroll 1
    for (int p = 0; p < 8; ++p) {
        // ======== f = f0 + 2p : fragments in B0 ========
        #pragma unroll
        for (int j = 0; j < 8; ++j) B1[j] = bp[j * 64];  // prefetch next f
        bp += 512;
        const float xvB = xp[1], wtB = wp[1], wlB = wtB * LN2;
        {
            short8 a0, a1;
            agen16t(wbase, xvA, wtA, wlA, a0, a1);
            acc[0] = __builtin_amdgcn_mfma_f32_16x16x32_bf16(a0, *(short8*)&B0[0], acc[0], 0, 0, 0);
            acc[1] = __builtin_amdgcn_mfma_f32_16x16x32_bf16(a0, *(short8*)&B0[1], acc[1], 0, 0, 0);
            acc[2] = __builtin_amdgcn_mfma_f32_16x16x32_bf16(a0, *(short8*)&B0[2], acc[2], 0, 0, 0);
            acc[3] = __builtin_amdgcn_mfma_f32_16x16x32_bf16(a0, *(short8*)&B0[3], acc[3], 0, 0, 0);
            acc[0] = __builtin_amdgcn_mfma_f32_16x16x32_bf16(a1, *(short8*)&B0[4], acc[0], 0, 0, 0);
            acc[1] = __builtin_amdgcn_mfma_f32_16x16x32_bf16(a1, *(short8*)&B0[5], acc[1], 0, 0, 0);
            acc[2] = __builtin_amdgcn_mfma_f32_16x16x32_bf16(a1, *(short8*)&B0[6], acc[2], 0, 0, 0);
            acc[3] = __builtin_amdgcn_mfma_f32_16x16x32_bf16(a1, *(short8*)&B0[7], acc[3], 0, 0, 0);
        }
        wbase += 128;

        // ======== f = f0 + 2p + 1 : fragments in B1 ========
        #pragma unroll
        for (int j = 0; j < 8; ++j) B0[j] = bp[j * 64];  // p==7: slot f0+16 (<=64), dead
        bp += 512;
        xvA = xp[2]; wtA = wp[2]; wlA = wtA * LN2;        // p==7: row pad, dead
        {
            short8 a0, a1;
            agen16t(wbase, xvB, wtB, wlB, a0, a1);
            acc[0] = __builtin_amdgcn_mfma_f32_16x16x32_bf16(a0, *(short8*)&B1[0], acc[0], 0, 0, 0);
            acc[1] = __builtin_amdgcn_mfma_f32_16x16x32_bf16(a0, *(short8*)&B1[1], acc[1], 0, 0, 0);
            acc[2] = __builtin_amdgcn_mfma_f32_16x16x32_bf16(a0, *(short8*)&B1[2], acc[2], 0, 0, 0);
            acc[3] = __builtin_amdgcn_mfma_f32_16x16x32_bf16(a0, *(short8*)&B1[3], acc[3], 0, 0, 0);
            acc[0] = __builtin_amdgcn_mfma_f32_16x16x32_bf16(a1, *(short8*)&B1[4], acc[0], 0, 0, 0);
            acc[1] = __builtin_amdgcn_mfma_f32_16x16x32_bf16(a1, *(short8*)&B1[5], acc[1], 0, 0, 0);
            acc[2] = __builtin_amdgcn_mfma_f32_16x16x32_bf16(a1, *(short8*)&B1[6], acc[2], 0, 0, 0);
            acc[3] = __builtin_amdgcn_mfma_f32_16x16x32_bf16(a1, *(short8*)&B1[7], acc[3], 0, 0, 0);
        }
        wbase += 128; xp += 2; wp += 2;
    }

    // ---- bias K-chunk: waves 0..3 = {eh = g} x {tile} ----
    if (wv < 4) {
        const int eh = g;
        const int e0 = eh * 32 + quad * 8;
        uint4 av;
        av.x = pk_bf16(wls[trow * 68 + e0 + 0], wls[trow * 68 + e0 + 1]);
        av.y = pk_bf16(wls[trow * 68 + e0 + 2], wls[trow * 68 + e0 + 3]);
        av.z = pk_bf16(wls[trow * 68 + e0 + 4], wls[trow * 68 + e0 + 5]);
        av.w = pk_bf16(wls[trow * 68 + e0 + 6], wls[trow * 68 + e0 + 7]);
        const short8 a = *(short8*)&av;
        const uint4* bq = (const uint4*)img + (size_t)64 * 512 + lane;
        #pragma unroll
        for (int u = 0; u < 4; ++u) {
            uint4 bv = bq[eh * 256 + u * 64];
            acc[u] = __builtin_amdgcn_mfma_f32_16x16x32_bf16(a, *(short8*)&bv, acc[u], 0, 0, 0);
        }
    }

    // ---- tail: per tile, reduce 4 wave-partials in wbped (weights done) ----
    __syncthreads();
    if (g >= 2) {
        float* p = wbped + tile * 2176 + (g - 2) * 1088;
        #pragma unroll
        for (int u = 0; u < 4; ++u)
            #pragma unroll
            for (int r = 0; r < 4; ++r)
                p[(quad * 4 + r) * 68 + u * 16 + m] = acc[u][r];
    }
    __syncthreads();
    if (g < 2) {
        const float* p = wbped + tile * 2176 + g * 1088;
        #pragma unroll
        for (int u = 0; u < 4; ++u)
            #pragma unroll
            for (int r = 0; r < 4; ++r)
                acc[u][r] += p[(quad * 4 + r) * 68 + u * 16 + m];
    }
    __syncthreads();
    if (g == 1) {
        float* p = wbped + tile * 2176;
        #pragma unroll
        for (int u = 0; u < 4; ++u)
            #pragma unroll
            for (int r = 0; r < 4; ++r)
                p[(quad * 4 + r) * 68 + u * 16 + m] = acc[u][r];
    }
    __syncthreads();
    if (g == 0) {
        float* p = wbped + tile * 2176;
        #pragma unroll
        for (int u = 0; u < 4; ++u)
            #pragma unroll
            for (int r = 0; r < 4; ++r) {
                const int idx = (quad * 4 + r) * 68 + u * 16 + m;
                p[idx] += acc[u][r];
            }
    }
    __syncthreads();

    // ---- final store: 32 tokens x 16 float4, coalesced ----
    {
        const int t = tid >> 4, kq = tid & 15;
        const float* srcp = wbped + (t >> 4) * 2176 + (t & 15) * 68 + kq * 4;
        *(float4*)(out + (size_t)(tokbase + t) * 64 + kq * 4) = *(const float4*)srcp;
    }
}

// ======================================================================
// Mid-tier (round-0 proven): 512 blocks x 512 thr, gating in-kernel.
// ======================================================================
__global__ __launch_bounds__(512, 4)
void moe_main(const float* __restrict__ x,   const float* __restrict__ s,
              const float* __restrict__ fw1, const float* __restrict__ fb1,
              const float* __restrict__ fw2, const float* __restrict__ fb2,
              const float* __restrict__ fw3, const float* __restrict__ fb3,
              const float* __restrict__ ew1, const float* __restrict__ eb1,
              const float* __restrict__ ew3, const float* __restrict__ eb3,
              const unsigned short* __restrict__ img,
              float* __restrict__ out)
{
    __shared__ __align__(16) float xls[32 * 68];
    __shared__ __align__(16) float wts[32 * 65];
    __shared__ __align__(16) float egs[32 * 64];
    __shared__ __align__(16) float ped0[4][16 * 68];
    __shared__ __align__(16) float ped1[4][16 * 68];

    const int tid = threadIdx.x;
    const int wv = tid >> 6, lane = tid & 63;
    const int m = tid & 15, quad = (tid >> 4) & 3;
    const int tokbase = blockIdx.x * 32;

    {
        const int t = tid >> 4, fq = (tid & 15) * 4;
        *(float4*)&xls[t * 68 + fq] =
            *(const float4*)(x + (size_t)(tokbase + t) * 64 + fq);
    }
    __syncthreads();

    {
        const int t0w = wv * 4;
        const float* sw = s + (size_t)(tokbase + t0w) * 32;
        float g[4];
        const float b0 = fb1[lane] + fb2[lane];
        #pragma unroll
        for (int t = 0; t < 4; ++t) g[t] = b0;
        for (int f = 0; f < 64; f += 4) {
            const float w0 = fw1[(f + 0) * 64 + lane];
            const float w1 = fw1[(f + 1) * 64 + lane];
            const float w2 = fw1[(f + 2) * 64 + lane];
            const float w3v = fw1[(f + 3) * 64 + lane];
            #pragma unroll
            for (int t = 0; t < 4; ++t) {
                const float4 xa = *(const float4*)&xls[(t0w + t) * 68 + f];
                g[t] = fmaf(xa.x, w0, fmaf(xa.y, w1, fmaf(xa.z, w2, fmaf(xa.w, w3v, g[t]))));
            }
        }
        for (int e = 0; e < 32; e += 4) {
            const float w0 = fw2[(e + 0) * 64 + lane];
            const float w1 = fw2[(e + 1) * 64 + lane];
            const float w2 = fw2[(e + 2) * 64 + lane];
            const float w3v = fw2[(e + 3) * 64 + lane];
            #pragma unroll
            for (int t = 0; t < 4; ++t) {
                const float4 sa = *(const float4*)(sw + t * 32 + e);
                g[t] = fmaf(sa.x, w0, fmaf(sa.y, w1, fmaf(sa.z, w2, fmaf(sa.w, w3v, g[t]))));
            }
        }
        #pragma unroll
        for (int t = 0; t < 4; ++t) egs[(t0w + t) * 64 + lane] = eluf(g[t]);

        float lg[4];
        const float b3 = fb3[lane];
        #pragma unroll
        for (int t = 0; t < 4; ++t) lg[t] = b3;
        for (int h = 0; h < 64; h += 4) {
            const float w0 = fw3[(h + 0) * 64 + lane];
            const float w1 = fw3[(h + 1) * 64 + lane];
            const float w2 = fw3[(h + 2) * 64 + lane];
            const float w3v = fw3[(h + 3) * 64 + lane];
            #pragma unroll
            for (int t = 0; t < 4; ++t) {
                const float4 ev = *(const float4*)&egs[(t0w + t) * 64 + h];
                lg[t] = fmaf(ev.x, w0, fmaf(ev.y, w1, fmaf(ev.z, w2, fmaf(ev.w, w3v, lg[t]))));
            }
        }
        #pragma unroll
        for (int t = 0; t < 4; ++t) {
            float mx = lg[t];
            #pragma unroll
            for (int off = 32; off > 0; off >>= 1) mx = fmaxf(mx, __shfl_xor(mx, off));
            const float p = __expf(lg[t] - mx);
            float sm = p;
            #pragma unroll
            for (int off = 32; off > 0; off >>= 1) sm += __shfl_xor(sm, off);
            wts[(t0w + t) * 65 + lane] = p / sm;
        }
    }
    __syncthreads();

    const int f0 = wv * 8;
    f32x4 acc0[4], acc1[4];
    #pragma unroll
    for (int u = 0; u < 4; ++u) {
        acc0[u] = (f32x4){0.f, 0.f, 0.f, 0.f};
        acc1[u] = (f32x4){0.f, 0.f, 0.f, 0.f};
    }

    const uint4* bp = (const uint4*)img + (size_t)f0 * 512 + lane;
    uint4  B[2][8];
    float4 W[2][4];
    float4 Bb[2][4];
    float  XV[2][2];
    float  WT[2][2];

    #pragma unroll
    for (int i = 0; i < 8; ++i) B[0][i] = bp[(i >> 2) * 256 + (i & 3) * 64];
    bp += 512;
    #pragma unroll
    for (int c = 0; c < 2; ++c) {
        W[0][c * 2 + 0]  = *(const float4*)(ew1 + f0 * 64 + c * 32 + quad * 8);
        W[0][c * 2 + 1]  = *(const float4*)(ew1 + f0 * 64 + c * 32 + quad * 8 + 4);
        Bb[0][c * 2 + 0] = *(const float4*)(eb1 + f0 * 64 + c * 32 + quad * 8);
        Bb[0][c * 2 + 1] = *(const float4*)(eb1 + f0 * 64 + c * 32 + quad * 8 + 4);
    }
    XV[0][0] = xls[m * 68 + f0];        WT[0][0] = wts[m * 65 + f0];
    XV[0][1] = xls[(16 + m) * 68 + f0]; WT[0][1] = wts[(16 + m) * 65 + f0];

    #pragma unroll
    for (int ff = 0; ff < 8; ++ff) {
        const int cur = ff & 1, nxt = cur ^ 1;
        if (ff < 7) {
            const int fn = f0 + ff + 1;
            #pragma unroll
            for (int i = 0; i < 8; ++i) B[nxt][i] = bp[(i >> 2) * 256 + (i & 3) * 64];
            bp += 512;
            #pragma unroll
            for (int c = 0; c < 2; ++c) {
                W[nxt][c * 2 + 0]  = *(const float4*)(ew1 + fn * 64 + c * 32 + quad * 8);
                W[nxt][c * 2 + 1]  = *(const float4*)(ew1 + fn * 64 + c * 32 + quad * 8 + 4);
                Bb[nxt][c * 2 + 0] = *(const float4*)(eb1 + fn * 64 + c * 32 + quad * 8);
                Bb[nxt][c * 2 + 1] = *(const float4*)(eb1 + fn * 64 + c * 32 + quad * 8 + 4);
            }
            XV[nxt][0] = xls[m * 68 + fn];        WT[nxt][0] = wts[m * 65 + fn];
            XV[nxt][1] = xls[(16 + m) * 68 + fn]; WT[nxt][1] = wts[(16 + m) * 65 + fn];
        }
        const float xv0 = XV[cur][0], wt0 = WT[cur][0];
        const float xv1 = XV[cur][1], wt1 = WT[cur][1];
        short8 a0[2], a1[2];
        #pragma unroll
        for (int c = 0; c < 2; ++c) {
            const float4 wa = W[cur][c * 2 + 0],  wb = W[cur][c * 2 + 1];
            const float4 ba = Bb[cur][c * 2 + 0], bb = Bb[cur][c * 2 + 1];
            uint4 v0, v1;
            v0.x = pack_bf16(wt0 * eluf(fmaf(xv0, wa.x, ba.x)),
                             wt0 * eluf(fmaf(xv0, wa.y, ba.y)));
            v0.y = pack_bf16(wt0 * eluf(fmaf(xv0, wa.z, ba.z)),
                             wt0 * eluf(fmaf(xv0, wa.w, ba.w)));
            v0.z = pack_bf16(wt0 * eluf(fmaf(xv0, wb.x, bb.x)),
                             wt0 * eluf(fmaf(xv0, wb.y, bb.y)));
            v0.w = pack_bf16(wt0 * eluf(fmaf(xv0, wb.z, bb.z)),
                             wt0 * eluf(fmaf(xv0, wb.w, bb.w)));
            v1.x = pack_bf16(wt1 * eluf(fmaf(xv1, wa.x, ba.x)),
                             wt1 * eluf(fmaf(xv1, wa.y, ba.y)));
            v1.y = pack_bf16(wt1 * eluf(fmaf(xv1, wa.z, ba.z)),
                             wt1 * eluf(fmaf(xv1, wa.w, ba.w)));
            v1.z = pack_bf16(wt1 * eluf(fmaf(xv1, wb.x, bb.x)),
                             wt1 * eluf(fmaf(xv1, wb.y, bb.y)));
            v1.w = pack_bf16(wt1 * eluf(fmaf(xv1, wb.z, bb.z)),
                             wt1 * eluf(fmaf(xv1, wb.w, bb.w)));
            a0[c] = *(short8*)&v0;
            a1[c] = *(short8*)&v1;
        }
        acc0[0] = __builtin_amdgcn_mfma_f32_16x16x32_bf16(a0[0], *(short8*)&B[cur][0], acc0[0], 0, 0, 0);
        acc0[1] = __builtin_amdgcn_mfma_f32_16x16x32_bf16(a0[0], *(short8*)&B[cur][1], acc0[1], 0, 0, 0);
        acc0[2] = __builtin_amdgcn_mfma_f32_16x16x32_bf16(a0[0], *(short8*)&B[cur][2], acc0[2], 0, 0, 0);
        acc0[3] = __builtin_amdgcn_mfma_f32_16x16x32_bf16(a0[0], *(short8*)&B[cur][3], acc0[3], 0, 0, 0);
        acc1[0] = __builtin_amdgcn_mfma_f32_16x16x32_bf16(a1[0], *(short8*)&B[cur][0], acc1[0], 0, 0, 0);
        acc1[1] = __builtin_amdgcn_mfma_f32_16x16x32_bf16(a1[0], *(short8*)&B[cur][1], acc1[1], 0, 0, 0);
        acc1[2] = __builtin_amdgcn_mfma_f32_16x16x32_bf16(a1[0], *(short8*)&B[cur][2], acc1[2], 0, 0, 0);
        acc1[3] = __builtin_amdgcn_mfma_f32_16x16x32_bf16(a1[0], *(short8*)&B[cur][3], acc1[3], 0, 0, 0);
        acc0[0] = __builtin_amdgcn_mfma_f32_16x16x32_bf16(a0[1], *(short8*)&B[cur][4], acc0[0], 0, 0, 0);
        acc0[1] = __builtin_amdgcn_mfma_f32_16x16x32_bf16(a0[1], *(short8*)&B[cur][5], acc0[1], 0, 0, 0);
        acc0[2] = __builtin_amdgcn_mfma_f32_16x16x32_bf16(a0[1], *(short8*)&B[cur][6], acc0[2], 0, 0, 0);
        acc0[3] = __builtin_amdgcn_mfma_f32_16x16x32_bf16(a0[1], *(short8*)&B[cur][7], acc0[3], 0, 0, 0);
        acc1[0] = __builtin_amdgcn_mfma_f32_16x16x32_bf16(a1[1], *(short8*)&B[cur][4], acc1[0], 0, 0, 0);
        acc1[1] = __builtin_amdgcn_mfma_f32_16x16x32_bf16(a1[1], *(short8*)&B[cur][5], acc1[1], 0, 0, 0);
        acc1[2] = __builtin_amdgcn_mfma_f32_16x16x32_bf16(a1[1], *(short8*)&B[cur][6], acc1[2], 0, 0, 0);
        acc1[3] = __builtin_amdgcn_mfma_f32_16x16x32_bf16(a1[1], *(short8*)&B[cur][7], acc1[3], 0, 0, 0);
    }

    if (wv < 4) {
        const int tile = wv >> 1, eh = wv & 1;
        const int e0 = eh * 32 + quad * 8;
        const int trow = tile * 16 + m;
        uint4 av;
        av.x = pack_bf16(wts[trow * 65 + e0 + 0], wts[trow * 65 + e0 + 1]);
        av.y = pack_bf16(wts[trow * 65 + e0 + 2], wts[trow * 65 + e0 + 3]);
        av.z = pack_bf16(wts[trow * 65 + e0 + 4], wts[trow * 65 + e0 + 5]);
        av.w = pack_bf16(wts[trow * 65 + e0 + 6], wts[trow * 65 + e0 + 7]);
        short8 a = *(short8*)&av;
        const uint4* bq = (const uint4*)img + (size_t)64 * 512;
        if (tile == 0) {
            #pragma unroll
            for (int u = 0; u < 4; ++u) {
                uint4 bv = bq[eh * 256 + u * 64 + lane];
                acc0[u] = __builtin_amdgcn_mfma_f32_16x16x32_bf16(a, *(short8*)&bv, acc0[u], 0, 0, 0);
            }
        } else {
            #pragma unroll
            for (int u = 0; u < 4; ++u) {
                uint4 bv = bq[eh * 256 + u * 64 + lane];
                acc1[u] = __builtin_amdgcn_mfma_f32_16x16x32_bf16(a, *(short8*)&bv, acc1[u], 0, 0, 0);
            }
        }
    }

    if (wv >= 4) {
        #pragma unroll
        for (int u = 0; u < 4; ++u)
            #pragma unroll
            for (int r = 0; r < 4; ++r) {
                const int idx = (quad * 4 + r) * 68 + u * 16 + m;
                ped0[wv - 4][idx] = acc0[u][r];
                ped1[wv - 4][idx] = acc1[u][r];
            }
    }
    __syncthreads();
    if (wv < 4) {
        #pragma unroll
        for (int u = 0; u < 4; ++u)
            #pragma unroll
            for (int r = 0; r < 4; ++r) {
                const int idx = (quad * 4 + r) * 68 + u * 16 + m;
                acc0[u][r] += ped0[wv][idx];
                acc1[u][r] += ped1[wv][idx];
            }
    }
    __syncthreads();
    if (wv == 2 || wv == 3) {
        #pragma unroll
        for (int u = 0; u < 4; ++u)
            #pragma unroll
            for (int r = 0; r < 4; ++r) {
                const int idx = (quad * 4 + r) * 68 + u * 16 + m;
                ped0[wv - 2][idx] = acc0[u][r];
                ped1[wv - 2][idx] = acc1[u][r];
            }
    }
    __syncthreads();
    if (wv < 2) {
        #pragma unroll
        for (int u = 0; u < 4; ++u)
            #pragma unroll
            for (int r = 0; r < 4; ++r) {
                const int idx = (quad * 4 + r) * 68 + u * 16 + m;
                acc0[u][r] += ped0[wv][idx];
                acc1[u][r] += ped1[wv][idx];
            }
    }
    __syncthreads();
    if (wv == 1) {
        #pragma unroll
        for (int u = 0; u < 4; ++u)
            #pragma unroll
            for (int r = 0; r < 4; ++r) {
                const int idx = (quad * 4 + r) * 68 + u * 16 + m;
                ped0[0][idx] = acc0[u][r];
                ped1[0][idx] = acc1[u][r];
            }
    }
    __syncthreads();
    if (wv == 0) {
        #pragma unroll
        for (int u = 0; u < 4; ++u)
            #pragma unroll
            for (int r = 0; r < 4; ++r) {
                const int idx = (quad * 4 + r) * 68 + u * 16 + m;
                ped0[0][idx] += acc0[u][r];
                ped1[0][idx] += acc1[u][r];
            }
    }
    __syncthreads();

    {
        const int t = tid >> 4, kq = tid & 15;
        const float* srcp = (t < 16) ? &ped0[0][t * 68 + kq * 4]
                                     : &ped1[0][(t - 16) * 68 + kq * 4];
        *(float4*)(out + (size_t)(tokbase + t) * 64 + kq * 4) = *(const float4*)srcp;
    }
}

// ======================================================================
// Fallback (ws-free), validated structure: 1024 blocks x 512 thr, 16 tok
// ======================================================================
__device__ __forceinline__ void gen_a_fb(const float* __restrict__ ew1,
                                         const float* __restrict__ eb1,
                                         int f, int quad, float xv, float wt,
                                         short8* a) {
    #pragma unroll
    for (int c = 0; c < 2; ++c) {
        const float* w1p = ew1 + f * 64 + c * 32 + quad * 8;
        const float* b1p = eb1 + f * 64 + c * 32 + quad * 8;
        const float4 w1a = *(const float4*)w1p, w1b = *(const float4*)(w1p + 4);
        const float4 b1a = *(const float4*)b1p, b1b = *(const float4*)(b1p + 4);
        uint4 av;
        av.x = pack_bf16(wt * eluf(fmaf(xv, w1a.x, b1a.x)),
                         wt * eluf(fmaf(xv, w1a.y, b1a.y)));
        av.y = pack_bf16(wt * eluf(fmaf(xv, w1a.z, b1a.z)),
                         wt * eluf(fmaf(xv, w1a.w, b1a.w)));
        av.z = pack_bf16(wt * eluf(fmaf(xv, w1b.x, b1b.x)),
                         wt * eluf(fmaf(xv, w1b.y, b1b.y)));
        av.w = pack_bf16(wt * eluf(fmaf(xv, w1b.z, b1b.z)),
                         wt * eluf(fmaf(xv, w1b.w, b1b.w)));
        a[c] = *(short8*)&av;
    }
}
__device__ __forceinline__ void gen_b_fp32(const float* __restrict__ w3f,
                                           int quad, int m, short8 b[2][4]) {
    #pragma unroll
    for (int c = 0; c < 2; ++c)
        #pragma unroll
        for (int u = 0; u < 4; ++u) {
            const float* wp = w3f + (size_t)(c * 32 + quad * 8) * 64 + u * 16 + m;
            uint4 v;
            v.x = pack_bf16(wp[0],   wp[64]);
            v.y = pack_bf16(wp[128], wp[192]);
            v.z = pack_bf16(wp[256], wp[320]);
            v.w = pack_bf16(wp[384], wp[448]);
            b[c][u] = *(short8*)&v;
        }
}

__global__ __launch_bounds__(512, 8)
void moe_fb(const float* __restrict__ x,   const float* __restrict__ s,
            const float* __restrict__ fw1, const float* __restrict__ fb1,
            const float* __restrict__ fw2, const float* __restrict__ fb2,
            const float* __restrict__ fw3, const float* __restrict__ fb3,
            const float* __restrict__ ew1, const float* __restrict__ eb1,
            const float* __restrict__ ew3, const float* __restrict__ eb3,
            float* __restrict__ out)
{
    __shared__ __align__(16) float xls[16 * 68];
    __shared__ __align__(16) float wts[16 * 65];
    __shared__ __align__(16) float egs[16 * 64];
    __shared__ __align__(16) float ped[4][16 * 68];

    const int tid = threadIdx.x;
    const int wv = tid >> 6, lane = tid & 63;
    const int tokbase = blockIdx.x * 16;

    if (tid < 256) {
        const int t = tid >> 4, fq = (tid & 15) * 4;
        *(float4*)&xls[t * 68 + fq] =
            *(const float4*)(x + (size_t)(tokbase + t) * 64 + fq);
    }
    __syncthreads();
    {
        const int t0w = wv * 2;
        const float* sw = s + (size_t)(tokbase + t0w) * 32;
        float g0, g1;
        g0 = g1 = fb1[lane] + fb2[lane];
        for (int ff = 0; ff < 64; ff += 4) {
            const float4 xa = *(const float4*)&xls[(t0w + 0) * 68 + ff];
            const float4 xb = *(const float4*)&xls[(t0w + 1) * 68 + ff];
            const float w0 = fw1[(ff + 0) * 64 + lane];
            const float w1 = fw1[(ff + 1) * 64 + lane];
            const float w2 = fw1[(ff + 2) * 64 + lane];
            const float w3v = fw1[(ff + 3) * 64 + lane];
            g0 = fmaf(xa.x, w0, fmaf(xa.y, w1, fmaf(xa.z, w2, fmaf(xa.w, w3v, g0))));
            g1 = fmaf(xb.x, w0, fmaf(xb.y, w1, fmaf(xb.z, w2, fmaf(xb.w, w3v, g1))));
        }
        for (int e = 0; e < 32; e += 4) {
            const float4 sa = *(const float4*)(sw + e);
            const float4 sb = *(const float4*)(sw + 32 + e);
            const float w0 = fw2[(e + 0) * 64 + lane];
            const float w1 = fw2[(e + 1) * 64 + lane];
            const float w2 = fw2[(e + 2) * 64 + lane];
            const float w3v = fw2[(e + 3) * 64 + lane];
            g0 = fmaf(sa.x, w0, fmaf(sa.y, w1, fmaf(sa.z, w2, fmaf(sa.w, w3v, g0))));
            g1 = fmaf(sb.x, w0, fmaf(sb.y, w1, fmaf(sb.z, w2, fmaf(sb.w, w3v, g1))));
        }
        egs[(t0w + 0) * 64 + lane] = eluf(g0);
        egs[(t0w + 1) * 64 + lane] = eluf(g1);
        float lg0 = fb3[lane], lg1 = lg0;
        for (int h = 0; h < 64; h += 4) {
            const float4 e0 = *(const float4*)&egs[(t0w + 0) * 64 + h];
            const float4 e1 = *(const float4*)&egs[(t0w + 1) * 64 + h];
            const float w0 = fw3[(h + 0) * 64 + lane];
            const float w1 = fw3[(h + 1) * 64 + lane];
            const float w2 = fw3[(h + 2) * 64 + lane];
            const float w3v = fw3[(h + 3) * 64 + lane];
            lg0 = fmaf(e0.x, w0, fmaf(e0.y, w1, fmaf(e0.z, w2, fmaf(e0.w, w3v, lg0))));
            lg1 = fmaf(e1.x, w0, fmaf(e1.y, w1, fmaf(e1.z, w2, fmaf(e1.w, w3v, lg1))));
        }
        float mx0 = lg0, mx1 = lg1;
        #pragma unroll
        for (int off = 32; off > 0; off >>= 1) {
            mx0 = fmaxf(mx0, __shfl_xor(mx0, off));
            mx1 = fmaxf(mx1, __shfl_xor(mx1, off));
        }
        const float p0 = __expf(lg0 - mx0), p1 = __expf(lg1 - mx1);
        float s0 = p0, s1 = p1;
        #pragma unroll
        for (int off = 32; off > 0; off >>= 1) {
            s0 += __shfl_xor(s0, off);
            s1 += __shfl_xor(s1, off);
        }
        wts[(t0w + 0) * 65 + lane] = p0 / s0;
        wts[(t0w + 1) * 65 + lane] = p1 / s1;
    }
    __syncthreads();

    const int m = tid & 15, quad = (tid >> 4) & 3;
    const int f0 = wv * 8;
    f32x4 acc[4];
    #pragma unroll
    for (int u = 0; u < 4; ++u) acc[u] = (f32x4){0.f, 0.f, 0.f, 0.f};

    #pragma unroll
    for (int ff = 0; ff < 8; ++ff) {
        const int fcur = f0 + ff;
        short8 b[2][4], a[2];
        gen_b_fp32(ew3 + (size_t)fcur * 4096, quad, m, b);
        gen_a_fb(ew1, eb1, fcur, quad, xls[m * 68 + fcur], wts[m * 65 + fcur], a);
        #pragma unroll
        for (int u = 0; u < 4; ++u) {
            acc[u] = __builtin_amdgcn_mfma_f32_16x16x32_bf16(a[0], b[0][u], acc[u], 0, 0, 0);
            acc[u] = __builtin_amdgcn_mfma_f32_16x16x32_bf16(a[1], b[1][u], acc[u], 0, 0, 0);
        }
    }
    if (wv < 2) {
        const int e0 = wv * 32 + quad * 8;
        uint4 av;
        av.x = pack_bf16(wts[m * 65 + e0 + 0], wts[m * 65 + e0 + 1]);
        av.y = pack_bf16(wts[m * 65 + e0 + 2], wts[m * 65 + e0 + 3]);
        av.z = pack_bf16(wts[m * 65 + e0 + 4], wts[m * 65 + e0 + 5]);
        av.w = pack_bf16(wts[m * 65 + e0 + 6], wts[m * 65 + e0 + 7]);
        short8 a = *(short8*)&av;
        #pragma unroll
        for (int u = 0; u < 4; ++u) {
            const float* wp = eb3 + (size_t)e0 * 64 + u * 16 + m;
            uint4 bv;
            bv.x = pack_bf16(wp[0],   wp[64]);
            bv.y = pack_bf16(wp[128], wp[192]);
            bv.z = pack_bf16(wp[256], wp[320]);
            bv.w = pack_bf16(wp[384], wp[448]);
            acc[u] = __builtin_amdgcn_mfma_f32_16x16x32_bf16(a, *(short8*)&bv, acc[u], 0, 0, 0);
        }
    }
    if (wv >= 4) {
        #pragma unroll
        for (int u = 0; u < 4; ++u)
            #pragma unroll
            for (int r = 0; r < 4; ++r)
                ped[wv - 4][(quad * 4 + r) * 68 + u * 16 + m] = acc[u][r];
    }
    __syncthreads();
    if (wv < 4) {
        #pragma unroll
        for (int u = 0; u < 4; ++u)
            #pragma unroll
            for (int r = 0; r < 4; ++r)
                acc[u][r] += ped[wv][(quad * 4 + r) * 68 + u * 16 + m];
    }
    __syncthreads();
    if (wv == 2 || wv == 3) {
        #pragma unroll
        for (int u = 0; u < 4; ++u)
            #pragma unroll
            for (int r = 0; r < 4; ++r)
                ped[wv - 2][(quad * 4 + r) * 68 + u * 16 + m] = acc[u][r];
    }
    __syncthreads();
    if (wv < 2) {
        #pragma unroll
        for (int u = 0; u < 4; ++u)
            #pragma unroll
            for (int r = 0; r < 4; ++r)
                acc[u][r] += ped[wv][(quad * 4 + r) * 68 + u * 16 + m];
    }
    __syncthreads();
    if (wv == 1) {
        #pragma unroll
        for (int u = 0; u < 4; ++u)
            #pragma unroll
            for (int r = 0; r < 4; ++r)
                ped[0][(quad * 4 + r) * 68 + u * 16 + m] = acc[u][r];
    }
    __syncthreads();
    if (wv == 0) {
        #pragma unroll
        for (int u = 0; u < 4; ++u)
            #pragma unroll
            for (int r = 0; r < 4; ++r)
                ped[0][(quad * 4 + r) * 68 + u * 16 + m] += acc[u][r];
    }
    __syncthreads();
    if (tid < 256) {
        const int t = tid >> 4, kq = tid & 15;
        float4 o = *(const float4*)&ped[0][t * 68 + kq * 4];
        *(float4*)(out + (size_t)(tokbase + t) * 64 + kq * 4) = o;
    }
}

extern "C" void kernel_launch(void* const* d_in, const int* in_sizes, int n_in,
                              void* d_out, int out_size, void* d_ws, size_t ws_size,
                              hipStream_t stream) {
    const float* x   = (const float*)d_in[0];
    const float* s   = (const float*)d_in[1];
    const float* fw1 = (const float*)d_in[2];
    const float* fb1 = (const float*)d_in[3];
    const float* fw2 = (const float*)d_in[4];
    const float* fb2 = (const float*)d_in[5];
    const float* fw3 = (const float*)d_in[6];
    const float* fb3 = (const float*)d_in[7];
    const float* ew1 = (const float*)d_in[8];
    const float* eb1 = (const float*)d_in[9];
    const float* ew3 = (const float*)d_in[10];
    const float* eb3 = (const float*)d_in[11];
    float* out = (float*)d_out;

    const size_t img_bytes = (size_t)65 * 4096 * sizeof(unsigned short); // 532,480
    const size_t wt_bytes  = (size_t)NTOK * 64 * sizeof(float);          // 4,194,304
    const bool al16 = (((uintptr_t)d_ws & 15) == 0);

    if (ws_size >= img_bytes + wt_bytes && al16) {
        unsigned short* img = (unsigned short*)d_ws;
        float* wtg = (float*)((char*)d_ws + img_bytes);
        prep_gate<<<dim3(65 + NTOK / 16), dim3(256), 0, stream>>>(
            ew3, eb3, x, s, fw1, fb1, fw2, fb2, fw3, fb3, img, wtg);
        moe_main8<<<dim3(NTOK / 32), dim3(512), 0, stream>>>(
            x, ew1, eb1, img, wtg, out);
    } else if (ws_size >= img_bytes && al16) {
        unsigned short* img = (unsigned short*)d_ws;
        prepass<<<dim3(65), dim3(256), 0, stream>>>(ew3, eb3, img);
        moe_main<<<dim3(NTOK / 32), dim3(512), 0, stream>>>(
            x, s, fw1, fb1, fw2, fb2, fw3, fb3, ew1, eb1, ew3, eb3, img, out);
    } else {
        moe_fb<<<dim3(NTOK / 16), dim3(512), 0, stream>>>(
            x, s, fw1, fb1, fw2, fb2, fw3, fb3, ew1, eb1, ew3, eb3, out);
    }
}

// Round 8
// 111.871 us; speedup vs baseline: 2.2105x; 1.0094x over previous
//
#include <hip/hip_runtime.h>
#include <hip/hip_bf16.h>
#include <math.h>

// B=32,T=512 -> NTOK=16384 tokens; F=64; H=64; E=32
#define NTOK 16384
#define LOG2E 1.44269504088896340736f
#define LN2   0.69314718055994530942f

typedef __attribute__((ext_vector_type(8))) short short8;   // 8 bf16 (MFMA A/B)
typedef __attribute__((ext_vector_type(4))) float f32x4;    // MFMA acc

__device__ __forceinline__ unsigned pack_bf16(float a, float b) {
    union { __hip_bfloat162 h; unsigned u; } cv;
    cv.h = __float22bfloat162_rn(make_float2(a, b));
    return cv.u;
}
// HW pack: v_cvt_pk_bf16_f32 (RNE, same as _rn for finite values). T12 recipe.
__device__ __forceinline__ unsigned pk_bf16(float a, float b) {
    unsigned r;
    asm("v_cvt_pk_bf16_f32 %0, %1, %2" : "=v"(r) : "v"(a), "v"(b));
    return r;
}
__device__ __forceinline__ float exp2_hw(float x) {
#if __has_builtin(__builtin_amdgcn_exp2f)
    return __builtin_amdgcn_exp2f(x);
#else
    return __expf(x * LN2);
#endif
}
__device__ __forceinline__ float eluf(float z) {
    return z > 0.0f ? z : (__expf(z) - 1.0f);
}

// Trimmed A-gen for one f, BOTH tiles, weights PRE-SCALED by LOG2E in LDS.
// One ds_read set serves both tiles. Per site: fma + min + max + exp2 + 2 fma.
// A00/A01 = tile0 c=0/c=1 fragments; A10/A11 = tile1.
__device__ __forceinline__ void agen16x2(const float* __restrict__ wb,
        float xv0, float wt0, float wl0,
        float xv1, float wt1, float wl1,
        short8& A00, short8& A01, short8& A10, short8& A11) {
    auto s0 = [&](float w, float b) -> float {
        const float z = fmaf(xv0, w, b);
        const float e = exp2_hw(fminf(z, 0.0f));
        return fmaf(wl0, fmaxf(z, 0.0f), fmaf(wt0, e, -wt0));
    };
    auto s1 = [&](float w, float b) -> float {
        const float z = fmaf(xv1, w, b);
        const float e = exp2_hw(fminf(z, 0.0f));
        return fmaf(wl1, fmaxf(z, 0.0f), fmaf(wt1, e, -wt1));
    };
    {
        const float4 wa  = *(const float4*)(wb);
        const float4 wv2 = *(const float4*)(wb + 4);
        const float4 ba  = *(const float4*)(wb + 64);
        const float4 bb  = *(const float4*)(wb + 68);
        uint4 v0, v1;
        v0.x = pk_bf16(s0(wa.x,  ba.x), s0(wa.y,  ba.y));
        v0.y = pk_bf16(s0(wa.z,  ba.z), s0(wa.w,  ba.w));
        v0.z = pk_bf16(s0(wv2.x, bb.x), s0(wv2.y, bb.y));
        v0.w = pk_bf16(s0(wv2.z, bb.z), s0(wv2.w, bb.w));
        v1.x = pk_bf16(s1(wa.x,  ba.x), s1(wa.y,  ba.y));
        v1.y = pk_bf16(s1(wa.z,  ba.z), s1(wa.w,  ba.w));
        v1.z = pk_bf16(s1(wv2.x, bb.x), s1(wv2.y, bb.y));
        v1.w = pk_bf16(s1(wv2.z, bb.z), s1(wv2.w, bb.w));
        A00 = *(short8*)&v0;
        A10 = *(short8*)&v1;
    }
    {
        const float4 wc = *(const float4*)(wb + 32);
        const float4 wd = *(const float4*)(wb + 36);
        const float4 bc = *(const float4*)(wb + 96);
        const float4 bd = *(const float4*)(wb + 100);
        uint4 v0, v1;
        v0.x = pk_bf16(s0(wc.x, bc.x), s0(wc.y, bc.y));
        v0.y = pk_bf16(s0(wc.z, bc.z), s0(wc.w, bc.w));
        v0.z = pk_bf16(s0(wd.x, bd.x), s0(wd.y, bd.y));
        v0.w = pk_bf16(s0(wd.z, bd.z), s0(wd.w, bd.w));
        v1.x = pk_bf16(s1(wc.x, bc.x), s1(wc.y, bc.y));
        v1.y = pk_bf16(s1(wc.z, bc.z), s1(wc.w, bc.w));
        v1.z = pk_bf16(s1(wd.x, bd.x), s1(wd.y, bd.y));
        v1.w = pk_bf16(s1(wd.z, bd.z), s1(wd.w, bd.w));
        A01 = *(short8*)&v0;
        A11 = *(short8*)&v1;
    }
}

// ---------------- prepass: fragment-major bf16 B images ----------------
__global__ __launch_bounds__(256)
void prepass(const float* __restrict__ ew3, const float* __restrict__ eb3,
             unsigned short* __restrict__ ws) {
    __shared__ float tile[64 * 65];
    const int bid = blockIdx.x, tid = threadIdx.x;
    const float* src = (bid < 64) ? (ew3 + (size_t)bid * 4096) : eb3;

    const int r = tid >> 2, c0 = (tid & 3) * 16;
    #pragma unroll
    for (int j = 0; j < 4; ++j) {
        float4 v = *(const float4*)(src + r * 64 + c0 + j * 4);
        tile[r * 65 + c0 + j * 4 + 0] = v.x;
        tile[r * 65 + c0 + j * 4 + 1] = v.y;
        tile[r * 65 + c0 + j * 4 + 2] = v.z;
        tile[r * 65 + c0 + j * 4 + 3] = v.w;
    }
    __syncthreads();

    uint4* dst = (uint4*)(ws + (size_t)bid * 4096);
    #pragma unroll
    for (int it = 0; it < 2; ++it) {
        const int idx = tid + it * 256;
        const int c = idx >> 8, u = (idx >> 6) & 3, l = idx & 63;
        const int mm = l & 15, q = (l >> 4) & 3;
        const int rb = c * 32 + q * 8, col = u * 16 + mm;
        unsigned pw[4];
        #pragma unroll
        for (int p = 0; p < 4; ++p)
            pw[p] = pack_bf16(tile[(rb + 2 * p) * 65 + col],
                              tile[(rb + 2 * p + 1) * 65 + col]);
        uint4 pk; pk.x = pw[0]; pk.y = pw[1]; pk.z = pw[2]; pk.w = pw[3];
        dst[idx] = pk;
    }
}

// ---------------- fused prepass + gating kernel ----------------
__global__ __launch_bounds__(256)
void prep_gate(const float* __restrict__ ew3, const float* __restrict__ eb3,
               const float* __restrict__ x,   const float* __restrict__ s,
               const float* __restrict__ fw1, const float* __restrict__ fb1,
               const float* __restrict__ fw2, const float* __restrict__ fb2,
               const float* __restrict__ fw3, const float* __restrict__ fb3,
               unsigned short* __restrict__ img, float* __restrict__ wtg)
{
    __shared__ float smem[64 * 65];
    const int tid = threadIdx.x;

    if (blockIdx.x < 65) {
        const int bid = blockIdx.x;
        const float* src = (bid < 64) ? (ew3 + (size_t)bid * 4096) : eb3;
        const int r = tid >> 2, c0 = (tid & 3) * 16;
        #pragma unroll
        for (int j = 0; j < 4; ++j) {
            float4 v = *(const float4*)(src + r * 64 + c0 + j * 4);
            smem[r * 65 + c0 + j * 4 + 0] = v.x;
            smem[r * 65 + c0 + j * 4 + 1] = v.y;
            smem[r * 65 + c0 + j * 4 + 2] = v.z;
            smem[r * 65 + c0 + j * 4 + 3] = v.w;
        }
        __syncthreads();
        uint4* dst = (uint4*)(img + (size_t)bid * 4096);
        #pragma unroll
        for (int it = 0; it < 2; ++it) {
            const int idx = tid + it * 256;
            const int c = idx >> 8, u = (idx >> 6) & 3, l = idx & 63;
            const int mm = l & 15, q = (l >> 4) & 3;
            const int rb = c * 32 + q * 8, col = u * 16 + mm;
            unsigned pw[4];
            #pragma unroll
            for (int p = 0; p < 4; ++p)
                pw[p] = pack_bf16(smem[(rb + 2 * p) * 65 + col],
                                  smem[(rb + 2 * p + 1) * 65 + col]);
            uint4 pk; pk.x = pw[0]; pk.y = pw[1]; pk.z = pw[2]; pk.w = pw[3];
            dst[idx] = pk;
        }
        return;
    }

    float* xls = smem;                 // [16][68]
    float* egs = smem + 16 * 68;       // [16][64]
    const int gb = blockIdx.x - 65;
    const int tokbase = gb * 16;
    const int wv = tid >> 6, lane = tid & 63;

    {
        const int t = tid >> 4, fq = (tid & 15) * 4;
        *(float4*)&xls[t * 68 + fq] =
            *(const float4*)(x + (size_t)(tokbase + t) * 64 + fq);
    }
    __syncthreads();

    const int t0w = wv * 4;
    const float* sw = s + (size_t)(tokbase + t0w) * 32;
    float g[4];
    const float b0 = fb1[lane] + fb2[lane];
    #pragma unroll
    for (int t = 0; t < 4; ++t) g[t] = b0;
    #pragma unroll 2
    for (int f = 0; f < 64; f += 4) {
        const float w0 = fw1[(f + 0) * 64 + lane];
        const float w1 = fw1[(f + 1) * 64 + lane];
        const float w2 = fw1[(f + 2) * 64 + lane];
        const float w3v = fw1[(f + 3) * 64 + lane];
        #pragma unroll
        for (int t = 0; t < 4; ++t) {
            const float4 xa = *(const float4*)&xls[(t0w + t) * 68 + f];
            g[t] = fmaf(xa.x, w0, fmaf(xa.y, w1, fmaf(xa.z, w2, fmaf(xa.w, w3v, g[t]))));
        }
    }
    #pragma unroll 2
    for (int e = 0; e < 32; e += 4) {
        const float w0 = fw2[(e + 0) * 64 + lane];
        const float w1 = fw2[(e + 1) * 64 + lane];
        const float w2 = fw2[(e + 2) * 64 + lane];
        const float w3v = fw2[(e + 3) * 64 + lane];
        #pragma unroll
        for (int t = 0; t < 4; ++t) {
            const float4 sa = *(const float4*)(sw + t * 32 + e);
            g[t] = fmaf(sa.x, w0, fmaf(sa.y, w1, fmaf(sa.z, w2, fmaf(sa.w, w3v, g[t]))));
        }
    }
    #pragma unroll
    for (int t = 0; t < 4; ++t) egs[(t0w + t) * 64 + lane] = eluf(g[t]);

    float lg[4];
    const float b3 = fb3[lane];
    #pragma unroll
    for (int t = 0; t < 4; ++t) lg[t] = b3;
    #pragma unroll 2
    for (int h = 0; h < 64; h += 4) {
        const float w0 = fw3[(h + 0) * 64 + lane];
        const float w1 = fw3[(h + 1) * 64 + lane];
        const float w2 = fw3[(h + 2) * 64 + lane];
        const float w3v = fw3[(h + 3) * 64 + lane];
        #pragma unroll
        for (int t = 0; t < 4; ++t) {
            const float4 ev = *(const float4*)&egs[(t0w + t) * 64 + h];
            lg[t] = fmaf(ev.x, w0, fmaf(ev.y, w1, fmaf(ev.z, w2, fmaf(ev.w, w3v, lg[t]))));
        }
    }
    #pragma unroll
    for (int t = 0; t < 4; ++t) {
        float mx = lg[t];
        #pragma unroll
        for (int off = 32; off > 0; off >>= 1) mx = fmaxf(mx, __shfl_xor(mx, off));
        const float p = __expf(lg[t] - mx);
        float sm = p;
        #pragma unroll
        for (int off = 32; off > 0; off >>= 1) sm += __shfl_xor(sm, off);
        wtg[(size_t)(tokbase + t0w + t) * 64 + lane] = p / sm;
    }
}

// ---------------- main kernel v9: original geometry + trimmed A-gen ----------------
// 512 blocks x 512 thr. Wave wv: f in [wv*8, wv*8+8), BOTH 16-token tiles.
// img read ONCE per block (512 KB vs v8's 1 MB); one ds_read weight set serves
// both tiles; 32-site A-gen (~400cy) covers the same-iteration 8 B-loads.
// Single B buffer (32 VGPR) + acc0/acc1 (32) => ~105 regs. Rolled loop.
// Summation grouping identical to the originally-validated moe_main.
__global__ __launch_bounds__(512, 4)
void moe_main9(const float* __restrict__ x,
               const float* __restrict__ ew1, const float* __restrict__ eb1,
               const unsigned short* __restrict__ img,
               const float* __restrict__ wtg,
               float* __restrict__ out)
{
    __shared__ __align__(16) float xls[32 * 68];      // x tile; tail: PED(1,3)
    __shared__ __align__(16) float wls[32 * 68];      // gates (live thru bias chunk)
    __shared__ __align__(16) float wbped[64 * 128];   // weights' (prescaled); tail: ped

    const int tid = threadIdx.x;
    const int wv = tid >> 6, lane = tid & 63;
    const int m = tid & 15, quad = (tid >> 4) & 3;
    const int f0 = wv * 8;
    const int tokbase = blockIdx.x * 32;

    // ---- stage x, gates + PRE-SCALED ew1/eb1 ----
    {
        const int t = tid >> 4, fq = (tid & 15) * 4;
        *(float4*)&xls[t * 68 + fq] =
            *(const float4*)(x + (size_t)(tokbase + t) * 64 + fq);
        *(float4*)&wls[t * 68 + fq] =
            *(const float4*)(wtg + (size_t)(tokbase + t) * 64 + fq);
        #pragma unroll
        for (int k = 0; k < 2; ++k) {
            const int idx = tid + k * 512;            // 0..1023
            const int fr = idx >> 4, c4 = (idx & 15) * 4;
            float4 wv4 = *(const float4*)(ew1 + fr * 64 + c4);
            float4 bv4 = *(const float4*)(eb1 + fr * 64 + c4);
            wv4.x *= LOG2E; wv4.y *= LOG2E; wv4.z *= LOG2E; wv4.w *= LOG2E;
            bv4.x *= LOG2E; bv4.y *= LOG2E; bv4.z *= LOG2E; bv4.w *= LOG2E;
            *(float4*)&wbped[fr * 128 + c4]      = wv4;
            *(float4*)&wbped[fr * 128 + 64 + c4] = bv4;
        }
    }
    __syncthreads();

    f32x4 acc0[4], acc1[4];
    #pragma unroll
    for (int u = 0; u < 4; ++u) {
        acc0[u] = (f32x4){0.f, 0.f, 0.f, 0.f};
        acc1[u] = (f32x4){0.f, 0.f, 0.f, 0.f};
    }

    // B-fragment j of slot f at img_u4[f*512 + j*64 + lane]
    const uint4* bp = (const uint4*)img + (size_t)f0 * 512 + lane;
    const float* wbase = &wbped[f0 * 128 + quad * 8];
    const float* xp0 = &xls[m * 68 + f0];
    const float* wp0 = &wls[m * 68 + f0];
    const float* xp1 = &xls[(16 + m) * 68 + f0];
    const float* wp1 = &wls[(16 + m) * 68 + f0];

    #pragma unroll 1
    for (int p = 0; p < 8; ++p) {
        // 1) issue this f's B loads (consumed after the 32-site A-gen below)
        uint4 B[8];
        #pragma unroll
        for (int j = 0; j < 8; ++j) B[j] = bp[j * 64];
        bp += 512;

        // 2) per-tile scalars (LDS)
        const float xv0 = xp0[p], wt0 = wp0[p], wl0 = wt0 * LN2;
        const float xv1 = xp1[p], wt1 = wp1[p], wl1 = wt1 * LN2;

        // 3) A-gen both tiles from one weight read (~400cy of issue -> covers B)
        short8 a00, a01, a10, a11;
        agen16x2(wbase, xv0, wt0, wl0, xv1, wt1, wl1, a00, a01, a10, a11);
        wbase += 128;

        // 4) 16 MFMA, original moe_main order
        acc0[0] = __builtin_amdgcn_mfma_f32_16x16x32_bf16(a00, *(short8*)&B[0], acc0[0], 0, 0, 0);
        acc0[1] = __builtin_amdgcn_mfma_f32_16x16x32_bf16(a00, *(short8*)&B[1], acc0[1], 0, 0, 0);
        acc0[2] = __builtin_amdgcn_mfma_f32_16x16x32_bf16(a00, *(short8*)&B[2], acc0[2], 0, 0, 0);
        acc0[3] = __builtin_amdgcn_mfma_f32_16x16x32_bf16(a00, *(short8*)&B[3], acc0[3], 0, 0, 0);
        acc1[0] = __builtin_amdgcn_mfma_f32_16x16x32_bf16(a10, *(short8*)&B[0], acc1[0], 0, 0, 0);
        acc1[1] = __builtin_amdgcn_mfma_f32_16x16x32_bf16(a10, *(short8*)&B[1], acc1[1], 0, 0, 0);
        acc1[2] = __builtin_amdgcn_mfma_f32_16x16x32_bf16(a10, *(short8*)&B[2], acc1[2], 0, 0, 0);
        acc1[3] = __builtin_amdgcn_mfma_f32_16x16x32_bf16(a10, *(short8*)&B[3], acc1[3], 0, 0, 0);
        acc0[0] = __builtin_amdgcn_mfma_f32_16x16x32_bf16(a01, *(short8*)&B[4], acc0[0], 0, 0, 0);
        acc0[1] = __builtin_amdgcn_mfma_f32_16x16x32_bf16(a01, *(short8*)&B[5], acc0[1], 0, 0, 0);
        acc0[2] = __builtin_amdgcn_mfma_f32_16x16x32_bf16(a01, *(short8*)&B[6], acc0[2], 0, 0, 0);
        acc0[3] = __builtin_amdgcn_mfma_f32_16x16x32_bf16(a01, *(short8*)&B[7], acc0[3], 0, 0, 0);
        acc1[0] = __builtin_amdgcn_mfma_f32_16x16x32_bf16(a11, *(short8*)&B[4], acc1[0], 0, 0, 0);
        acc1[1] = __builtin_amdgcn_mfma_f32_16x16x32_bf16(a11, *(short8*)&B[5], acc1[1], 0, 0, 0);
        acc1[2] = __builtin_amdgcn_mfma_f32_16x16x32_bf16(a11, *(short8*)&B[6], acc1[2], 0, 0, 0);
        acc1[3] = __builtin_amdgcn_mfma_f32_16x16x32_bf16(a11, *(short8*)&B[7], acc1[3], 0, 0, 0);
    }

    // ---- bias K-chunk: waves 0..3 = {tile} x {e-half} (original mapping) ----
    if (wv < 4) {
        const int tile = wv >> 1, eh = wv & 1;
        const int e0 = eh * 32 + quad * 8;
        const int trow = tile * 16 + m;
        uint4 av;
        av.x = pk_bf16(wls[trow * 68 + e0 + 0], wls[trow * 68 + e0 + 1]);
        av.y = pk_bf16(wls[trow * 68 + e0 + 2], wls[trow * 68 + e0 + 3]);
        av.z = pk_bf16(wls[trow * 68 + e0 + 4], wls[trow * 68 + e0 + 5]);
        av.w = pk_bf16(wls[trow * 68 + e0 + 6], wls[trow * 68 + e0 + 7]);
        const short8 a = *(short8*)&av;
        const uint4* bq = (const uint4*)img + (size_t)64 * 512 + lane;
        if (tile == 0) {
            #pragma unroll
            for (int u = 0; u < 4; ++u) {
                uint4 bv = bq[eh * 256 + u * 64];
                acc0[u] = __builtin_amdgcn_mfma_f32_16x16x32_bf16(a, *(short8*)&bv, acc0[u], 0, 0, 0);
            }
        } else {
            #pragma unroll
            for (int u = 0; u < 4; ++u) {
                uint4 bv = bq[eh * 256 + u * 64];
                acc1[u] = __builtin_amdgcn_mfma_f32_16x16x32_bf16(a, *(short8*)&bv, acc1[u], 0, 0, 0);
            }
        }
    }

    // ---- tail: 6-barrier tree over 8 wave-partials, both tiles ----
    // PED(0,s) = wbped + s*1088 (s=0..3)
    // PED(1,s) = wbped + 4352 + s*1088 (s=0..2); PED(1,3) = xls (dead)
    __syncthreads();     // all f-loop reads of wbped/xls and bias reads of wls done
    if (wv >= 4) {
        const int s = wv - 4;
        float* p0 = wbped + s * 1088;
        float* p1 = (s < 3) ? (wbped + 4352 + s * 1088) : xls;
        #pragma unroll
        for (int u = 0; u < 4; ++u)
            #pragma unroll
            for (int r = 0; r < 4; ++r) {
                const int idx = (quad * 4 + r) * 68 + u * 16 + m;
                p0[idx] = acc0[u][r];
                p1[idx] = acc1[u][r];
            }
    }
    __syncthreads();
    if (wv < 4) {
        const int s = wv;
        const float* p0 = wbped + s * 1088;
        const float* p1 = (s < 3) ? (wbped + 4352 + s * 1088) : xls;
        #pragma unroll
        for (int u = 0; u < 4; ++u)
            #pragma unroll
            for (int r = 0; r < 4; ++r) {
                const int idx = (quad * 4 + r) * 68 + u * 16 + m;
                acc0[u][r] += p0[idx];
                acc1[u][r] += p1[idx];
            }
    }
    __syncthreads();
    if (wv == 2 || wv == 3) {
        const int s = wv - 2;
        float* p0 = wbped + s * 1088;
        float* p1 = wbped + 4352 + s * 1088;
        #pragma unroll
        for (int u = 0; u < 4; ++u)
            #pragma unroll
            for (int r = 0; r < 4; ++r) {
                const int idx = (quad * 4 + r) * 68 + u * 16 + m;
                p0[idx] = acc0[u][r];
                p1[idx] = acc1[u][r];
            }
    }
    __syncthreads();
    if (wv < 2) {
        const float* p0 = wbped + wv * 1088;
        const float* p1 = wbped + 4352 + wv * 1088;
        #pragma unroll
        for (int u = 0; u < 4; ++u)
            #pragma unroll
            for (int r = 0; r < 4; ++r) {
                const int idx = (quad * 4 + r) * 68 + u * 16 + m;
                acc0[u][r] += p0[idx];
                acc1[u][r] += p1[idx];
            }
    }
    __syncthreads();
    if (wv == 1) {
        float* p0 = wbped;
        float* p1 = wbped + 4352;
        #pragma unroll
        for (int u = 0; u < 4; ++u)
            #pragma unroll
            for (int r = 0; r < 4; ++r) {
                const int idx = (quad * 4 + r) * 68 + u * 16 + m;
                p0[idx] = acc0[u][r];
                p1[idx] = acc1[u][r];
            }
    }
    __syncthreads();
    if (wv == 0) {
        float* p0 = wbped;
        float* p1 = wbped + 4352;
        #pragma unroll
        for (int u = 0; u < 4; ++u)
            #pragma unroll
            for (int r = 0; r < 4; ++r) {
                const int idx = (quad * 4 + r) * 68 + u * 16 + m;
                p0[idx] += acc0[u][r];
                p1[idx] += acc1[u][r];
            }
    }
    __syncthreads();

    // ---- final store: 32 tokens x 16 float4, coalesced ----
    {
        const int t = tid >> 4, kq = tid & 15;
        const float* srcp = (t < 16) ? (wbped + t * 68 + kq * 4)
                                     : (wbped + 4352 + (t - 16) * 68 + kq * 4);
        *(float4*)(out + (size_t)(tokbase + t) * 64 + kq * 4) = *(const float4*)srcp;
    }
}

// ======================================================================
// Mid-tier (round-0 proven): 512 blocks x 512 thr, gating in-kernel.
// ======================================================================
__global__ __launch_bounds__(512, 4)
void moe_main(const float* __restrict__ x,   const float* __restrict__ s,
              const float* __restrict__ fw1, const float* __restrict__ fb1,
              const float* __restrict__ fw2, const float* __restrict__ fb2,
              const float* __restrict__ fw3, const float* __restrict__ fb3,
              const float* __restrict__ ew1, const float* __restrict__ eb1,
              const float* __restrict__ ew3, const float* __restrict__ eb3,
              const unsigned short* __restrict__ img,
              float* __restrict__ out)
{
    __shared__ __align__(16) float xls[32 * 68];
    __shared__ __align__(16) float wts[32 * 65];
    __shared__ __align__(16) float egs[32 * 64];
    __shared__ __align__(16) float ped0[4][16 * 68];
    __shared__ __align__(16) float ped1[4][16 * 68];

    const int tid = threadIdx.x;
    const int wv = tid >> 6, lane = tid & 63;
    const int m = tid & 15, quad = (tid >> 4) & 3;
    const int tokbase = blockIdx.x * 32;

    {
        const int t = tid >> 4, fq = (tid & 15) * 4;
        *(float4*)&xls[t * 68 + fq] =
            *(const float4*)(x + (size_t)(tokbase + t) * 64 + fq);
    }
    __syncthreads();

    {
        const int t0w = wv * 4;
        const float* sw = s + (size_t)(tokbase + t0w) * 32;
        float g[4];
        const float b0 = fb1[lane] + fb2[lane];
        #pragma unroll
        for (int t = 0; t < 4; ++t) g[t] = b0;
        for (int f = 0; f < 64; f += 4) {
            const float w0 = fw1[(f + 0) * 64 + lane];
            const float w1 = fw1[(f + 1) * 64 + lane];
            const float w2 = fw1[(f + 2) * 64 + lane];
            const float w3v = fw1[(f + 3) * 64 + lane];
            #pragma unroll
            for (int t = 0; t < 4; ++t) {
                const float4 xa = *(const float4*)&xls[(t0w + t) * 68 + f];
                g[t] = fmaf(xa.x, w0, fmaf(xa.y, w1, fmaf(xa.z, w2, fmaf(xa.w, w3v, g[t]))));
            }
        }
        for (int e = 0; e < 32; e += 4) {
            const float w0 = fw2[(e + 0) * 64 + lane];
            const float w1 = fw2[(e + 1) * 64 + lane];
            const float w2 = fw2[(e + 2) * 64 + lane];
            const float w3v = fw2[(e + 3) * 64 + lane];
            #pragma unroll
            for (int t = 0; t < 4; ++t) {
                const float4 sa = *(const float4*)(sw + t * 32 + e);
                g[t] = fmaf(sa.x, w0, fmaf(sa.y, w1, fmaf(sa.z, w2, fmaf(sa.w, w3v, g[t]))));
            }
        }
        #pragma unroll
        for (int t = 0; t < 4; ++t) egs[(t0w + t) * 64 + lane] = eluf(g[t]);

        float lg[4];
        const float b3 = fb3[lane];
        #pragma unroll
        for (int t = 0; t < 4; ++t) lg[t] = b3;
        for (int h = 0; h < 64; h += 4) {
            const float w0 = fw3[(h + 0) * 64 + lane];
            const float w1 = fw3[(h + 1) * 64 + lane];
            const float w2 = fw3[(h + 2) * 64 + lane];
            const float w3v = fw3[(h + 3) * 64 + lane];
            #pragma unroll
            for (int t = 0; t < 4; ++t) {
                const float4 ev = *(const float4*)&egs[(t0w + t) * 64 + h];
                lg[t] = fmaf(ev.x, w0, fmaf(ev.y, w1, fmaf(ev.z, w2, fmaf(ev.w, w3v, lg[t]))));
            }
        }
        #pragma unroll
        for (int t = 0; t < 4; ++t) {
            float mx = lg[t];
            #pragma unroll
            for (int off = 32; off > 0; off >>= 1) mx = fmaxf(mx, __shfl_xor(mx, off));
            const float p = __expf(lg[t] - mx);
            float sm = p;
            #pragma unroll
            for (int off = 32; off > 0; off >>= 1) sm += __shfl_xor(sm, off);
            wts[(t0w + t) * 65 + lane] = p / sm;
        }
    }
    __syncthreads();

    const int f0 = wv * 8;
    f32x4 acc0[4], acc1[4];
    #pragma unroll
    for (int u = 0; u < 4; ++u) {
        acc0[u] = (f32x4){0.f, 0.f, 0.f, 0.f};
        acc1[u] = (f32x4){0.f, 0.f, 0.f, 0.f};
    }

    const uint4* bp = (const uint4*)img + (size_t)f0 * 512 + lane;
    uint4  B[2][8];
    float4 W[2][4];
    float4 Bb[2][4];
    float  XV[2][2];
    float  WT[2][2];

    #pragma unroll
    for (int i = 0; i < 8; ++i) B[0][i] = bp[(i >> 2) * 256 + (i & 3) * 64];
    bp += 512;
    #pragma unroll
    for (int c = 0; c < 2; ++c) {
        W[0][c * 2 + 0]  = *(const float4*)(ew1 + f0 * 64 + c * 32 + quad * 8);
        W[0][c * 2 + 1]  = *(const float4*)(ew1 + f0 * 64 + c * 32 + quad * 8 + 4);
        Bb[0][c * 2 + 0] = *(const float4*)(eb1 + f0 * 64 + c * 32 + quad * 8);
        Bb[0][c * 2 + 1] = *(const float4*)(eb1 + f0 * 64 + c * 32 + quad * 8 + 4);
    }
    XV[0][0] = xls[m * 68 + f0];        WT[0][0] = wts[m * 65 + f0];
    XV[0][1] = xls[(16 + m) * 68 + f0]; WT[0][1] = wts[(16 + m) * 65 + f0];

    #pragma unroll
    for (int ff = 0; ff < 8; ++ff) {
        const int cur = ff & 1, nxt = cur ^ 1;
        if (ff < 7) {
            const int fn = f0 + ff + 1;
            #pragma unroll
            for (int i = 0; i < 8; ++i) B[nxt][i] = bp[(i >> 2) * 256 + (i & 3) * 64];
            bp += 512;
            #pragma unroll
            for (int c = 0; c < 2; ++c) {
                W[nxt][c * 2 + 0]  = *(const float4*)(ew1 + fn * 64 + c * 32 + quad * 8);
                W[nxt][c * 2 + 1]  = *(const float4*)(ew1 + fn * 64 + c * 32 + quad * 8 + 4);
                Bb[nxt][c * 2 + 0] = *(const float4*)(eb1 + fn * 64 + c * 32 + quad * 8);
                Bb[nxt][c * 2 + 1] = *(const float4*)(eb1 + fn * 64 + c * 32 + quad * 8 + 4);
            }
            XV[nxt][0] = xls[m * 68 + fn];        WT[nxt][0] = wts[m * 65 + fn];
            XV[nxt][1] = xls[(16 + m) * 68 + fn]; WT[nxt][1] = wts[(16 + m) * 65 + fn];
        }
        const float xv0 = XV[cur][0], wt0 = WT[cur][0];
        const float xv1 = XV[cur][1], wt1 = WT[cur][1];
        short8 a0[2], a1[2];
        #pragma unroll
        for (int c = 0; c < 2; ++c) {
            const float4 wa = W[cur][c * 2 + 0],  wb = W[cur][c * 2 + 1];
            const float4 ba = Bb[cur][c * 2 + 0], bb = Bb[cur][c * 2 + 1];
            uint4 v0, v1;
            v0.x = pack_bf16(wt0 * eluf(fmaf(xv0, wa.x, ba.x)),
                             wt0 * eluf(fmaf(xv0, wa.y, ba.y)));
            v0.y = pack_bf16(wt0 * eluf(fmaf(xv0, wa.z, ba.z)),
                             wt0 * eluf(fmaf(xv0, wa.w, ba.w)));
            v0.z = pack_bf16(wt0 * eluf(fmaf(xv0, wb.x, bb.x)),
                             wt0 * eluf(fmaf(xv0, wb.y, bb.y)));
            v0.w = pack_bf16(wt0 * eluf(fmaf(xv0, wb.z, bb.z)),
                             wt0 * eluf(fmaf(xv0, wb.w, bb.w)));
            v1.x = pack_bf16(wt1 * eluf(fmaf(xv1, wa.x, ba.x)),
                             wt1 * eluf(fmaf(xv1, wa.y, ba.y)));
            v1.y = pack_bf16(wt1 * eluf(fmaf(xv1, wa.z, ba.z)),
                             wt1 * eluf(fmaf(xv1, wa.w, ba.w)));
            v1.z = pack_bf16(wt1 * eluf(fmaf(xv1, wb.x, bb.x)),
                             wt1 * eluf(fmaf(xv1, wb.y, bb.y)));
            v1.w = pack_bf16(wt1 * eluf(fmaf(xv1, wb.z, bb.z)),
                             wt1 * eluf(fmaf(xv1, wb.w, bb.w)));
            a0[c] = *(short8*)&v0;
            a1[c] = *(short8*)&v1;
        }
        acc0[0] = __builtin_amdgcn_mfma_f32_16x16x32_bf16(a0[0], *(short8*)&B[cur][0], acc0[0], 0, 0, 0);
        acc0[1] = __builtin_amdgcn_mfma_f32_16x16x32_bf16(a0[0], *(short8*)&B[cur][1], acc0[1], 0, 0, 0);
        acc0[2] = __builtin_amdgcn_mfma_f32_16x16x32_bf16(a0[0], *(short8*)&B[cur][2], acc0[2], 0, 0, 0);
        acc0[3] = __builtin_amdgcn_mfma_f32_16x16x32_bf16(a0[0], *(short8*)&B[cur][3], acc0[3], 0, 0, 0);
        acc1[0] = __builtin_amdgcn_mfma_f32_16x16x32_bf16(a1[0], *(short8*)&B[cur][0], acc1[0], 0, 0, 0);
        acc1[1] = __builtin_amdgcn_mfma_f32_16x16x32_bf16(a1[0], *(short8*)&B[cur][1], acc1[1], 0, 0, 0);
        acc1[2] = __builtin_amdgcn_mfma_f32_16x16x32_bf16(a1[0], *(short8*)&B[cur][2], acc1[2], 0, 0, 0);
        acc1[3] = __builtin_amdgcn_mfma_f32_16x16x32_bf16(a1[0], *(short8*)&B[cur][3], acc1[3], 0, 0, 0);
        acc0[0] = __builtin_amdgcn_mfma_f32_16x16x32_bf16(a0[1], *(short8*)&B[cur][4], acc0[0], 0, 0, 0);
        acc0[1] = __builtin_amdgcn_mfma_f32_16x16x32_bf16(a0[1], *(short8*)&B[cur][5], acc0[1], 0, 0, 0);
        acc0[2] = __builtin_amdgcn_mfma_f32_16x16x32_bf16(a0[1], *(short8*)&B[cur][6], acc0[2], 0, 0, 0);
        acc0[3] = __builtin_amdgcn_mfma_f32_16x16x32_bf16(a0[1], *(short8*)&B[cur][7], acc0[3], 0, 0, 0);
        acc1[0] = __builtin_amdgcn_mfma_f32_16x16x32_bf16(a1[1], *(short8*)&B[cur][4], acc1[0], 0, 0, 0);
        acc1[1] = __builtin_amdgcn_mfma_f32_16x16x32_bf16(a1[1], *(short8*)&B[cur][5], acc1[1], 0, 0, 0);
        acc1[2] = __builtin_amdgcn_mfma_f32_16x16x32_bf16(a1[1], *(short8*)&B[cur][6], acc1[2], 0, 0, 0);
        acc1[3] = __builtin_amdgcn_mfma_f32_16x16x32_bf16(a1[1], *(short8*)&B[cur][7], acc1[3], 0, 0, 0);
    }

    if (wv < 4) {
        const int tile = wv >> 1, eh = wv & 1;
        const int e0 = eh * 32 + quad * 8;
        const int trow = tile * 16 + m;
        uint4 av;
        av.x = pack_bf16(wts[trow * 65 + e0 + 0], wts[trow * 65 + e0 + 1]);
        av.y = pack_bf16(wts[trow * 65 + e0 + 2], wts[trow * 65 + e0 + 3]);
        av.z = pack_bf16(wts[trow * 65 + e0 + 4], wts[trow * 65 + e0 + 5]);
        av.w = pack_bf16(wts[trow * 65 + e0 + 6], wts[trow * 65 + e0 + 7]);
        short8 a = *(short8*)&av;
        const uint4* bq = (const uint4*)img + (size_t)64 * 512;
        if (tile == 0) {
            #pragma unroll
            for (int u = 0; u < 4; ++u) {
                uint4 bv = bq[eh * 256 + u * 64 + lane];
                acc0[u] = __builtin_amdgcn_mfma_f32_16x16x32_bf16(a, *(short8*)&bv, acc0[u], 0, 0, 0);
            }
        } else {
            #pragma unroll
            for (int u = 0; u < 4; ++u) {
                uint4 bv = bq[eh * 256 + u * 64 + lane];
                acc1[u] = __builtin_amdgcn_mfma_f32_16x16x32_bf16(a, *(short8*)&bv, acc1[u], 0, 0, 0);
            }
        }
    }

    if (wv >= 4) {
        #pragma unroll
        for (int u = 0; u < 4; ++u)
            #pragma unroll
            for (int r = 0; r < 4; ++r) {
                const int idx = (quad * 4 + r) * 68 + u * 16 + m;
                ped0[wv - 4][idx] = acc0[u][r];
                ped1[wv - 4][idx] = acc1[u][r];
            }
    }
    __syncthreads();
    if (wv < 4) {
        #pragma unroll
        for (int u = 0; u < 4; ++u)
            #pragma unroll
            for (int r = 0; r < 4; ++r) {
                const int idx = (quad * 4 + r) * 68 + u * 16 + m;
                acc0[u][r] += ped0[wv][idx];
                acc1[u][r] += ped1[wv][idx];
            }
    }
    __syncthreads();
    if (wv == 2 || wv == 3) {
        #pragma unroll
        for (int u = 0; u < 4; ++u)
            #pragma unroll
            for (int r = 0; r < 4; ++r) {
                const int idx = (quad * 4 + r) * 68 + u * 16 + m;
                ped0[wv - 2][idx] = acc0[u][r];
                ped1[wv - 2][idx] = acc1[u][r];
            }
    }
    __syncthreads();
    if (wv < 2) {
        #pragma unroll
        for (int u = 0; u < 4; ++u)
            #pragma unroll
            for (int r = 0; r < 4; ++r) {
                const int idx = (quad * 4 + r) * 68 + u * 16 + m;
                acc0[u][r] += ped0[wv][idx];
                acc1[u][r] += ped1[wv][idx];
            }
    }
    __syncthreads();
    if (wv == 1) {
        #pragma unroll
        for (int u = 0; u < 4; ++u)
            #pragma unroll
            for (int r = 0; r < 4; ++r) {
                const int idx = (quad * 4 + r) * 68 + u * 16 + m;
                ped0[0][idx] = acc0[u][r];
                ped1[0][idx] = acc1[u][r];
            }
    }
    __syncthreads();
    if (wv == 0) {
        #pragma unroll
        for (int u = 0; u < 4; ++u)
            #pragma unroll
            for (int r = 0; r < 4; ++r) {
                const int idx = (quad * 4 + r) * 68 + u * 16 + m;
                ped0[0][idx] += acc0[u][r];
                ped1[0][idx] += acc1[u][r];
            }
    }
    __syncthreads();

    {
        const int t = tid >> 4, kq = tid & 15;
        const float* srcp = (t < 16) ? &ped0[0][t * 68 + kq * 4]
                                     : &ped1[0][(t - 16) * 68 + kq * 4];
        *(float4*)(out + (size_t)(tokbase + t) * 64 + kq * 4) = *(const float4*)srcp;
    }
}

// ======================================================================
// Fallback (ws-free), validated structure: 1024 blocks x 512 thr, 16 tok
// ======================================================================
__device__ __forceinline__ void gen_a_fb(const float* __restrict__ ew1,
                                         const float* __restrict__ eb1,
                                         int f, int quad, float xv, float wt,
                                         short8* a) {
    #pragma unroll
    for (int c = 0; c < 2; ++c) {
        const float* w1p = ew1 + f * 64 + c * 32 + quad * 8;
        const float* b1p = eb1 + f * 64 + c * 32 + quad * 8;
        const float4 w1a = *(const float4*)w1p, w1b = *(const float4*)(w1p + 4);
        const float4 b1a = *(const float4*)b1p, b1b = *(const float4*)(b1p + 4);
        uint4 av;
        av.x = pack_bf16(wt * eluf(fmaf(xv, w1a.x, b1a.x)),
                         wt * eluf(fmaf(xv, w1a.y, b1a.y)));
        av.y = pack_bf16(wt * eluf(fmaf(xv, w1a.z, b1a.z)),
                         wt * eluf(fmaf(xv, w1a.w, b1a.w)));
        av.z = pack_bf16(wt * eluf(fmaf(xv, w1b.x, b1b.x)),
                         wt * eluf(fmaf(xv, w1b.y, b1b.y)));
        av.w = pack_bf16(wt * eluf(fmaf(xv, w1b.z, b1b.z)),
                         wt * eluf(fmaf(xv, w1b.w, b1b.w)));
        a[c] = *(short8*)&av;
    }
}
__device__ __forceinline__ void gen_b_fp32(const float* __restrict__ w3f,
                                           int quad, int m, short8 b[2][4]) {
    #pragma unroll
    for (int c = 0; c < 2; ++c)
        #pragma unroll
        for (int u = 0; u < 4; ++u) {
            const float* wp = w3f + (size_t)(c * 32 + quad * 8) * 64 + u * 16 + m;
            uint4 v;
            v.x = pack_bf16(wp[0],   wp[64]);
            v.y = pack_bf16(wp[128], wp[192]);
            v.z = pack_bf16(wp[256], wp[320]);
            v.w = pack_bf16(wp[384], wp[448]);
            b[c][u] = *(short8*)&v;
        }
}

__global__ __launch_bounds__(512, 8)
void moe_fb(const float* __restrict__ x,   const float* __restrict__ s,
            const float* __restrict__ fw1, const float* __restrict__ fb1,
            const float* __restrict__ fw2, const float* __restrict__ fb2,
            const float* __restrict__ fw3, const float* __restrict__ fb3,
            const float* __restrict__ ew1, const float* __restrict__ eb1,
            const float* __restrict__ ew3, const float* __restrict__ eb3,
            float* __restrict__ out)
{
    __shared__ __align__(16) float xls[16 * 68];
    __shared__ __align__(16) float wts[16 * 65];
    __shared__ __align__(16) float egs[16 * 64];
    __shared__ __align__(16) float ped[4][16 * 68];

    const int tid = threadIdx.x;
    const int wv = tid >> 6, lane = tid & 63;
    const int tokbase = blockIdx.x * 16;

    if (tid < 256) {
        const int t = tid >> 4, fq = (tid & 15) * 4;
        *(float4*)&xls[t * 68 + fq] =
            *(const float4*)(x + (size_t)(tokbase + t) * 64 + fq);
    }
    __syncthreads();
    {
        const int t0w = wv * 2;
        const float* sw = s + (size_t)(tokbase + t0w) * 32;
        float g0, g1;
        g0 = g1 = fb1[lane] + fb2[lane];
        for (int ff = 0; ff < 64; ff += 4) {
            const float4 xa = *(const float4*)&xls[(t0w + 0) * 68 + ff];
            const float4 xb = *(const float4*)&xls[(t0w + 1) * 68 + ff];
            const float w0 = fw1[(ff + 0) * 64 + lane];
            const float w1 = fw1[(ff + 1) * 64 + lane];
            const float w2 = fw1[(ff + 2) * 64 + lane];
            const float w3v = fw1[(ff + 3) * 64 + lane];
            g0 = fmaf(xa.x, w0, fmaf(xa.y, w1, fmaf(xa.z, w2, fmaf(xa.w, w3v, g0))));
            g1 = fmaf(xb.x, w0, fmaf(xb.y, w1, fmaf(xb.z, w2, fmaf(xb.w, w3v, g1))));
        }
        for (int e = 0; e < 32; e += 4) {
            const float4 sa = *(const float4*)(sw + e);
            const float4 sb = *(const float4*)(sw + 32 + e);
            const float w0 = fw2[(e + 0) * 64 + lane];
            const float w1 = fw2[(e + 1) * 64 + lane];
            const float w2 = fw2[(e + 2) * 64 + lane];
            const float w3v = fw2[(e + 3) * 64 + lane];
            g0 = fmaf(sa.x, w0, fmaf(sa.y, w1, fmaf(sa.z, w2, fmaf(sa.w, w3v, g0))));
            g1 = fmaf(sb.x, w0, fmaf(sb.y, w1, fmaf(sb.z, w2, fmaf(sb.w, w3v, g1))));
        }
        egs[(t0w + 0) * 64 + lane] = eluf(g0);
        egs[(t0w + 1) * 64 + lane] = eluf(g1);
        float lg0 = fb3[lane], lg1 = lg0;
        for (int h = 0; h < 64; h += 4) {
            const float4 e0 = *(const float4*)&egs[(t0w + 0) * 64 + h];
            const float4 e1 = *(const float4*)&egs[(t0w + 1) * 64 + h];
            const float w0 = fw3[(h + 0) * 64 + lane];
            const float w1 = fw3[(h + 1) * 64 + lane];
            const float w2 = fw3[(h + 2) * 64 + lane];
            const float w3v = fw3[(h + 3) * 64 + lane];
            lg0 = fmaf(e0.x, w0, fmaf(e0.y, w1, fmaf(e0.z, w2, fmaf(e0.w, w3v, lg0))));
            lg1 = fmaf(e1.x, w0, fmaf(e1.y, w1, fmaf(e1.z, w2, fmaf(e1.w, w3v, lg1))));
        }
        float mx0 = lg0, mx1 = lg1;
        #pragma unroll
        for (int off = 32; off > 0; off >>= 1) {
            mx0 = fmaxf(mx0, __shfl_xor(mx0, off));
            mx1 = fmaxf(mx1, __shfl_xor(mx1, off));
        }
        const float p0 = __expf(lg0 - mx0), p1 = __expf(lg1 - mx1);
        float s0 = p0, s1 = p1;
        #pragma unroll
        for (int off = 32; off > 0; off >>= 1) {
            s0 += __shfl_xor(s0, off);
            s1 += __shfl_xor(s1, off);
        }
        wts[(t0w + 0) * 65 + lane] = p0 / s0;
        wts[(t0w + 1) * 65 + lane] = p1 / s1;
    }
    __syncthreads();

    const int m = tid & 15, quad = (tid >> 4) & 3;
    const int f0 = wv * 8;
    f32x4 acc[4];
    #pragma unroll
    for (int u = 0; u < 4; ++u) acc[u] = (f32x4){0.f, 0.f, 0.f, 0.f};

    #pragma unroll
    for (int ff = 0; ff < 8; ++ff) {
        const int fcur = f0 + ff;
        short8 b[2][4], a[2];
        gen_b_fp32(ew3 + (size_t)fcur * 4096, quad, m, b);
        gen_a_fb(ew1, eb1, fcur, quad, xls[m * 68 + fcur], wts[m * 65 + fcur], a);
        #pragma unroll
        for (int u = 0; u < 4; ++u) {
            acc[u] = __builtin_amdgcn_mfma_f32_16x16x32_bf16(a[0], b[0][u], acc[u], 0, 0, 0);
            acc[u] = __builtin_amdgcn_mfma_f32_16x16x32_bf16(a[1], b[1][u], acc[u], 0, 0, 0);
        }
    }
    if (wv < 2) {
        const int e0 = wv * 32 + quad * 8;
        uint4 av;
        av.x = pack_bf16(wts[m * 65 + e0 + 0], wts[m * 65 + e0 + 1]);
        av.y = pack_bf16(wts[m * 65 + e0 + 2], wts[m * 65 + e0 + 3]);
        av.z = pack_bf16(wts[m * 65 + e0 + 4], wts[m * 65 + e0 + 5]);
        av.w = pack_bf16(wts[m * 65 + e0 + 6], wts[m * 65 + e0 + 7]);
        short8 a = *(short8*)&av;
        #pragma unroll
        for (int u = 0; u < 4; ++u) {
            const float* wp = eb3 + (size_t)e0 * 64 + u * 16 + m;
            uint4 bv;
            bv.x = pack_bf16(wp[0],   wp[64]);
            bv.y = pack_bf16(wp[128], wp[192]);
            bv.z = pack_bf16(wp[256], wp[320]);
            bv.w = pack_bf16(wp[384], wp[448]);
            acc[u] = __builtin_amdgcn_mfma_f32_16x16x32_bf16(a, *(short8*)&bv, acc[u], 0, 0, 0);
        }
    }
    if (wv >= 4) {
        #pragma unroll
        for (int u = 0; u < 4; ++u)
            #pragma unroll
            for (int r = 0; r < 4; ++r)
                ped[wv - 4][(quad * 4 + r) * 68 + u * 16 + m] = acc[u][r];
    }
    __syncthreads();
    if (wv < 4) {
        #pragma unroll
        for (int u = 0; u < 4; ++u)
            #pragma unroll
            for (int r = 0; r < 4; ++r)
                acc[u][r] += ped[wv][(quad * 4 + r) * 68 + u * 16 + m];
    }
    __syncthreads();
    if (wv == 2 || wv == 3) {
        #pragma unroll
        for (int u = 0; u < 4; ++u)
            #pragma unroll
            for (int r = 0; r < 4; ++r)
                ped[wv - 2][(quad * 4 + r) * 68 + u * 16 + m] = acc[u][r];
    }
    __syncthreads();
    if (wv < 2) {
        #pragma unroll
        for (int u = 0; u < 4; ++u)
            #pragma unroll
            for (int r = 0; r < 4; ++r)
                acc[u][r] += ped[wv][(quad * 4 + r) * 68 + u * 16 + m];
    }
    __syncthreads();
    if (wv == 1) {
        #pragma unroll
        for (int u = 0; u < 4; ++u)
            #pragma unroll
            for (int r = 0; r < 4; ++r)
                ped[0][(quad * 4 + r) * 68 + u * 16 + m] = acc[u][r];
    }
    __syncthreads();
    if (wv == 0) {
        #pragma unroll
        for (int u = 0; u < 4; ++u)
            #pragma unroll
            for (int r = 0; r < 4; ++r)
                ped[0][(quad * 4 + r) * 68 + u * 16 + m] += acc[u][r];
    }
    __syncthreads();
    if (tid < 256) {
        const int t = tid >> 4, kq = tid & 15;
        float4 o = *(const float4*)&ped[0][t * 68 + kq * 4];
        *(float4*)(out + (size_t)(tokbase + t) * 64 + kq * 4) = o;
    }
}

extern "C" void kernel_launch(void* const* d_in, const int* in_sizes, int n_in,
                              void* d_out, int out_size, void* d_ws, size_t ws_size,
                              hipStream_t stream) {
    const float* x   = (const float*)d_in[0];
    const float* s   = (const float*)d_in[1];
    const float* fw1 = (const float*)d_in[2];
    const float* fb1 = (const float*)d_in[3];
    const float* fw2 = (const float*)d_in[4];
    const float* fb2 = (const float*)d_in[5];
    const float* fw3 = (const float*)d_in[6];
    const float* fb3 = (const float*)d_in[7];
    const float* ew1 = (const float*)d_in[8];
    const float* eb1 = (const float*)d_in[9];
    const float* ew3 = (const float*)d_in[10];
    const float* eb3 = (const float*)d_in[11];
    float* out = (float*)d_out;

    const size_t img_bytes = (size_t)65 * 4096 * sizeof(unsigned short); // 532,480
    const size_t wt_bytes  = (size_t)NTOK * 64 * sizeof(float);          // 4,194,304
    const bool al16 = (((uintptr_t)d_ws & 15) == 0);

    if (ws_size >= img_bytes + wt_bytes && al16) {
        unsigned short* img = (unsigned short*)d_ws;
        float* wtg = (float*)((char*)d_ws + img_bytes);
        prep_gate<<<dim3(65 + NTOK / 16), dim3(256), 0, stream>>>(
            ew3, eb3, x, s, fw1, fb1, fw2, fb2, fw3, fb3, img, wtg);
        moe_main9<<<dim3(NTOK / 32), dim3(512), 0, stream>>>(
            x, ew1, eb1, img, wtg, out);
    } else if (ws_size >= img_bytes && al16) {
        unsigned short* img = (unsigned short*)d_ws;
        prepass<<<dim3(65), dim3(256), 0, stream>>>(ew3, eb3, img);
        moe_main<<<dim3(NTOK / 32), dim3(512), 0, stream>>>(
            x, s, fw1, fb1, fw2, fb2, fw3, fb3, ew1, eb1, ew3, eb3, img, out);
    } else {
        moe_fb<<<dim3(NTOK / 16), dim3(512), 0, stream>>>(
            x, s, fw1, fb1, fw2, fb2, fw3, fb3, ew1, eb1, ew3, eb3, out);
    }
}